// Round 6
// baseline (258.060 us; speedup 1.0000x reference)
//
#include <hip/hip_runtime.h>
#include <cmath>

#define EMB 256
#define NHEAD 8
#define HD 32
#define A_LEN 512
#define TOK 32768

typedef __bf16 bf16_t;
typedef __bf16 bf16x8 __attribute__((ext_vector_type(8)));
typedef __bf16 bf16x4 __attribute__((ext_vector_type(4)));
typedef float floatx4 __attribute__((ext_vector_type(4)));

#define MFMA16(a, b, c) __builtin_amdgcn_mfma_f32_16x16x32_bf16((a), (b), (c), 0, 0, 0)

// Fast exact-gelu: erf via Abramowitz-Stegun 7.1.26 (|err|<1.5e-7, far below
// bf16 storage rounding). ~12 VALU + 1 exp vs ~30 for libm erff.
__device__ __forceinline__ float gelu_f(float x) {
    float ax = fabsf(x) * 0.7071067811865476f;
    float t = __builtin_amdgcn_rcpf(fmaf(0.3275911f, ax, 1.0f));
    float poly = t * fmaf(t, fmaf(t, fmaf(t, fmaf(t, 1.061405429f, -1.453152027f),
                          1.421413741f), -0.284496736f), 0.254829592f);
    float erfv = 1.0f - poly * __expf(-ax * ax);
    erfv = copysignf(erfv, x);
    return 0.5f * x * (1.0f + erfv);
}

// ---------------------------------------------------------------------------
// Setup: weight_norm all 4 weights -> bf16 rows in Wall, plus RoPE cos/sin
// tables. Blocks 0..1535: one wave per weight row. Blocks 1536..1663: table.
// ---------------------------------------------------------------------------
__global__ __launch_bounds__(64) void setup_kernel(
    const float* __restrict__ proj_v, const float* __restrict__ proj_g,
    const float* __restrict__ ff_v, const float* __restrict__ ff_g,
    const float* __restrict__ w1_v, const float* __restrict__ w1_g,
    const float* __restrict__ w2_v, const float* __restrict__ w2_g,
    bf16_t* __restrict__ Wall, float* __restrict__ ctab,
    float* __restrict__ stab) {
    int b = blockIdx.x;
    int lane = threadIdx.x;
    if (b < 1536) {
        const float* v; const float* g; int r;
        if (b < 768)       { v = proj_v; g = proj_g; r = b; }
        else if (b < 1024) { v = ff_v;   g = ff_g;   r = b - 768; }
        else if (b < 1280) { v = w1_v;   g = w1_g;   r = b - 1024; }
        else               { v = w2_v;   g = w2_g;   r = b - 1280; }
        const floatx4* vr = (const floatx4*)(v + (size_t)r * 256);
        floatx4 x = vr[lane];
        float ss = x[0] * x[0] + x[1] * x[1] + x[2] * x[2] + x[3] * x[3];
#pragma unroll
        for (int off = 32; off >= 1; off >>= 1) ss += __shfl_xor(ss, off);
        float sc = g[r] * rsqrtf(ss);
        bf16x4 o;
        o[0] = (bf16_t)(x[0] * sc); o[1] = (bf16_t)(x[1] * sc);
        o[2] = (bf16_t)(x[2] * sc); o[3] = (bf16_t)(x[3] * sc);
        ((bf16x4*)(Wall + (size_t)b * 256))[lane] = o;
    } else {
        int idx = (b - 1536) * 64 + lane;     // 0..8191 = a*16 + i
        int a = idx >> 4, i = idx & 15;
        float freq = expf(-(float)(2 * i) * 0.2878231366242558f); // ln(1e4)/32
        float ang = (float)a * freq;
        ctab[idx] = cosf(ang);
        stab[idx] = sinf(ang);
    }
}

// ---------------------------------------------------------------------------
// QKV: 32 tokens/block (1024 blocks -> 4 blocks/CU). LN1 -> bf16 xns (LDS).
// q/k sections: W as MFMA *A*-operand so each lane's 4 acc regs are 4
// CONSECUTIVE output dims of one token -> RoPE pairs are in-lane (no
// shuffles, float2 table loads, single f32 rounding). Bias folded into
// MFMA C-init. Results staged in LDS [32][264] and flushed with 16B/lane
// fully-coalesced stores. v keeps transposed staging -> [bh][d][a].
// LDS 16.9 + 17.0 = 33.9 KB -> 4 blocks/CU.
// ---------------------------------------------------------------------------
__global__ __launch_bounds__(256, 4) void qkv_kernel(
    const float* __restrict__ z, const float* __restrict__ ln_g,
    const float* __restrict__ ln_b, const bf16_t* __restrict__ W,
    const float* __restrict__ pb, const float* __restrict__ ctab,
    const float* __restrict__ stab, bf16_t* __restrict__ qbf,
    bf16_t* __restrict__ kbf, bf16_t* __restrict__ vtb) {
    __shared__ bf16_t xns[32 * 264];   // 16.9 KB
    __shared__ bf16_t stg[8704];       // 17.0 KB (q/k: [32][264]; v: [256][34])
    int tid = threadIdx.x;
    int t0 = blockIdx.x * 32;
    int bu = t0 >> 9, a0 = t0 & 511;

    // ---- LN1 -> xns ----
#pragma unroll
    for (int it = 0; it < 2; ++it) {
        int row = it * 16 + (tid >> 4);
        int sub = tid & 15;
        const floatx4* zr = (const floatx4*)(z + (size_t)(t0 + row) * 256 + sub * 16);
        floatx4 v0 = zr[0], v1 = zr[1], v2 = zr[2], v3 = zr[3];
        float vals[16];
        ((floatx4*)vals)[0] = v0; ((floatx4*)vals)[1] = v1;
        ((floatx4*)vals)[2] = v2; ((floatx4*)vals)[3] = v3;
        float s = 0.f, q2 = 0.f;
#pragma unroll
        for (int i = 0; i < 16; ++i) { s += vals[i]; q2 += vals[i] * vals[i]; }
#pragma unroll
        for (int off = 8; off >= 1; off >>= 1) {
            s += __shfl_xor(s, off);
            q2 += __shfl_xor(q2, off);
        }
        float mu = s * (1.f / 256.f);
        float inv = rsqrtf(q2 * (1.f / 256.f) - mu * mu + 1e-5f);
        int cb = sub * 16;
        bf16x8 o0, o1;
#pragma unroll
        for (int i = 0; i < 8; ++i)
            o0[i] = (bf16_t)((vals[i] - mu) * inv * ln_g[cb + i] + ln_b[cb + i]);
#pragma unroll
        for (int i = 0; i < 8; ++i)
            o1[i] = (bf16_t)((vals[8 + i] - mu) * inv * ln_g[cb + 8 + i] + ln_b[cb + 8 + i]);
        *(bf16x8*)&xns[row * 264 + cb] = o0;
        *(bf16x8*)&xns[row * 264 + cb + 8] = o1;
    }
    __syncthreads();

    int wv = tid >> 6, lane = tid & 63, quad = lane >> 4, lidx = lane & 15;

    // ---- q/k sections (sec 0 = q, 1 = k): W rows as A-operand ----
#pragma unroll 1
    for (int sec = 0; sec < 2; ++sec) {
        bf16_t* __restrict__ dst = (sec == 0) ? qbf : kbf;
        floatx4 acc[4][2];
#pragma unroll
        for (int ntl = 0; ntl < 4; ++ntl) {
            int cb = wv * 64 + ntl * 16;           // within-sec column base
            int ht = cb >> 5;
            floatx4 b4 = *(const floatx4*)&pb[ht * 96 + sec * 32 + (cb & 31) + quad * 4];
            acc[ntl][0] = b4; acc[ntl][1] = b4;
        }
#pragma unroll 2
        for (int kc = 0; kc < 8; ++kc) {
            bf16x8 x0 = *(const bf16x8*)&xns[lidx * 264 + kc * 32 + quad * 8];
            bf16x8 x1 = *(const bf16x8*)&xns[(16 + lidx) * 264 + kc * 32 + quad * 8];
#pragma unroll
            for (int ntl = 0; ntl < 4; ++ntl) {
                int cb = wv * 64 + ntl * 16;
                int ht = cb >> 5;
                int n = ht * 96 + sec * 32 + (cb & 31) + lidx;
                bf16x8 wf = *(const bf16x8*)&W[(size_t)n * 256 + kc * 32 + quad * 8];
                acc[ntl][0] = MFMA16(wf, x0, acc[ntl][0]);
                acc[ntl][1] = MFMA16(wf, x1, acc[ntl][1]);
            }
        }
        // RoPE in-lane (acc regs r=0..3 are consecutive d), stage to LDS
        float scl = (sec == 0) ? 0.17677669529663687f : 1.0f;
#pragma unroll
        for (int ntl = 0; ntl < 4; ++ntl) {
            int cb = wv * 64 + ntl * 16;
            int d0 = (cb & 31) + quad * 4;         // multiple of 4
            int fi = d0 >> 1;                      // even, <= 14
#pragma unroll
            for (int tt = 0; tt < 2; ++tt) {
                int al = tt * 16 + lidx;
                int a = a0 + al;
                float cs0 = ctab[a * 16 + fi],     cs1 = ctab[a * 16 + fi + 1];
                float sn0 = stab[a * 16 + fi],     sn1 = stab[a * 16 + fi + 1];
                floatx4 v = acc[ntl][tt];
                bf16x4 o;
                o[0] = (bf16_t)((v[0] * cs0 - v[1] * sn0) * scl);
                o[1] = (bf16_t)((v[1] * cs0 + v[0] * sn0) * scl);
                o[2] = (bf16_t)((v[2] * cs1 - v[3] * sn1) * scl);
                o[3] = (bf16_t)((v[3] * cs1 + v[2] * sn1) * scl);
                *(bf16x4*)&stg[al * 264 + cb + quad * 4] = o;
            }
        }
        __syncthreads();
        // coalesced flush: 1024 x 16B chunks; wave writes 1KB contiguous
#pragma unroll
        for (int i = 0; i < 4; ++i) {
            int cid = i * 256 + tid;
            int chunk = cid & 3, al = (cid >> 2) & 31, ht = cid >> 7;
            bf16x8 vv = *(const bf16x8*)&stg[al * 264 + ht * 32 + chunk * 8];
            *(bf16x8*)&dst[((size_t)((bu * 8 + ht) * 512 + a0 + al)) * 32 + chunk * 8] = vv;
        }
        __syncthreads();
    }

    // ---- v section: X as A-operand; stage transposed [vcol][a_loc] ----
    {
        floatx4 acc[4][2];
#pragma unroll
        for (int ntl = 0; ntl < 4; ++ntl) {
            int cb = wv * 64 + ntl * 16;
            int ht = cb >> 5;
            float b = pb[ht * 96 + 64 + (cb & 31) + lidx];
            acc[ntl][0] = (floatx4){b, b, b, b};
            acc[ntl][1] = (floatx4){b, b, b, b};
        }
#pragma unroll 2
        for (int kc = 0; kc < 8; ++kc) {
            bf16x8 x0 = *(const bf16x8*)&xns[lidx * 264 + kc * 32 + quad * 8];
            bf16x8 x1 = *(const bf16x8*)&xns[(16 + lidx) * 264 + kc * 32 + quad * 8];
#pragma unroll
            for (int ntl = 0; ntl < 4; ++ntl) {
                int cb = wv * 64 + ntl * 16;
                int ht = cb >> 5;
                int n = ht * 96 + 64 + (cb & 31) + lidx;
                bf16x8 wf = *(const bf16x8*)&W[(size_t)n * 256 + kc * 32 + quad * 8];
                acc[ntl][0] = MFMA16(x0, wf, acc[ntl][0]);
                acc[ntl][1] = MFMA16(x1, wf, acc[ntl][1]);
            }
        }
#pragma unroll
        for (int ntl = 0; ntl < 4; ++ntl) {
            int vcol = wv * 64 + ntl * 16 + lidx;
#pragma unroll
            for (int tt = 0; tt < 2; ++tt)
#pragma unroll
                for (int r = 0; r < 4; ++r)
                    stg[vcol * 34 + tt * 16 + quad * 4 + r] = (bf16_t)acc[ntl][tt][r];
        }
        __syncthreads();
#pragma unroll
        for (int i = 0; i < 4; ++i) {
            int cid = i * 256 + tid;
            int chunk = cid & 3, vcol = cid >> 2;
            bf16x8 vv = *(const bf16x8*)&stg[vcol * 34 + chunk * 8];
            *(bf16x8*)&vtb[((size_t)(bu * 256 + vcol)) * 512 + a0 + chunk * 8] = vv;
        }
    }
}

// ---------------------------------------------------------------------------
// Attention: one block (512 thr = 8 waves) per (bu,h). Swapped QK^T
// (mfma(K,Q)) + permuted K-row feed so each lane's 16 exp'd scores ARE the
// PV A-fragment in-lane: zero P LDS traffic, zero cross-lane P exchange.
// Row-sums accumulate in-lane (query = lidx); 2-shuffle reduce + 4 shfl
// redistribution per q-tile. exp(s-8) via MFMA C-init (shift-invariant).
// All arrays loop-local & statically indexed (no scratch). LDS 64 KB.
// ---------------------------------------------------------------------------
__global__ __launch_bounds__(512, 4) void attn_kernel(
    const bf16_t* __restrict__ qbf, const bf16_t* __restrict__ kbf,
    const bf16_t* __restrict__ vtb, bf16_t* __restrict__ ob) {
    __shared__ bf16_t Kls[512 * 32];      // 32 KB
    __shared__ bf16_t Vt[32 * 512];       // 32 KB
    int tid = threadIdx.x;
    int wv = tid >> 6, lane = tid & 63, quad = lane >> 4, lidx = lane & 15;
    int bh = blockIdx.x;
    int bu = bh >> 3, h = bh & 7;
    size_t hb = (size_t)bh * (A_LEN * HD);

    // ---- stage K (row-swizzled) and V^T (pre-transposed in global) ----
#pragma unroll
    for (int i = 0; i < 4; ++i) {
        int c = tid + i * 512;            // 16B chunk id, 0..2047
        int key = c >> 2, blk = c & 3;
        bf16x8 kv = *(const bf16x8*)&kbf[hb + (size_t)c * 8];
        *(bf16x8*)&Kls[key * 32 + ((blk ^ (key & 3)) << 3)] = kv;
        int vrow = c >> 6, vblk = c & 63;
        bf16x8 vv = *(const bf16x8*)&vtb[hb + (size_t)c * 8];
        *(bf16x8*)&Vt[vrow * 512 + ((vblk ^ (vrow & 7)) << 3)] = vv;
    }
    __syncthreads();

    const floatx4 cm8 = (floatx4){-8.f, -8.f, -8.f, -8.f};
    const floatx4 zero4 = (floatx4){0.f, 0.f, 0.f, 0.f};
    // permuted K-row base within a 64-key block (t adds (t&1)*4 + (t>>1)*32)
    int krow = ((lidx >> 2) << 3) + (lidx & 3);
    int kswz = (quad ^ (lidx & 3)) << 3;

#pragma unroll 1
    for (int mt = 0; mt < 4; ++mt) {
        int q0 = wv * 64 + mt * 16;
        // Q fragment: content valid as B-operand (same lane layout as A)
        bf16x8 qfrag = *(const bf16x8*)&qbf[hb + (size_t)(q0 + lidx) * 32 + quad * 8];
        float l_ = 0.f;
        floatx4 Oacc[2];
        Oacc[0] = zero4; Oacc[1] = zero4;

#pragma unroll 1
        for (int kc = 0; kc < 8; ++kc) {
            // QK^T swapped: D[key][query]; lane holds query=lidx,
            // keys = quad*8 + (t&1)*4 + j + (t>>1)*32 (via permuted row feed)
            floatx4 sc[4];
#pragma unroll
            for (int t = 0; t < 4; ++t) {
                int row = kc * 64 + (t >> 1) * 32 + ((t & 1) << 2) + krow;
                bf16x8 kf = *(const bf16x8*)&Kls[row * 32 + kswz];
                sc[t] = MFMA16(kf, qfrag, cm8);   // s - 8 folded into C
            }
            float p[4][4];
#pragma unroll
            for (int t = 0; t < 4; ++t)
#pragma unroll
                for (int r = 0; r < 4; ++r) p[t][r] = __expf(sc[t][r]);
            // in-lane row-sum partial (query = lidx)
#pragma unroll
            for (int t = 0; t < 4; ++t)
                l_ += (p[t][0] + p[t][1]) + (p[t][2] + p[t][3]);
            // pack P directly as PV A-fragments (all in-lane)
            bf16x8 pa0, pa1;
#pragma unroll
            for (int r = 0; r < 4; ++r) {
                pa0[r]     = (bf16_t)p[0][r];
                pa0[4 + r] = (bf16_t)p[1][r];
                pa1[r]     = (bf16_t)p[2][r];
                pa1[4 + r] = (bf16_t)p[3][r];
            }
            // PV
#pragma unroll
            for (int nt = 0; nt < 2; ++nt) {
                int vr = nt * 16 + lidx;
                bf16x8 vf0 = *(const bf16x8*)&Vt[vr * 512 +
                    ((kc * 8 + ((0 * 4 + quad) ^ (lidx & 7))) << 3)];
                Oacc[nt] = MFMA16(pa0, vf0, Oacc[nt]);
                bf16x8 vf1 = *(const bf16x8*)&Vt[vr * 512 +
                    ((kc * 8 + ((1 * 4 + quad) ^ (lidx & 7))) << 3)];
                Oacc[nt] = MFMA16(pa1, vf1, Oacc[nt]);
            }
        }

        // ---- epilogue: reduce L across quads, redistribute, store ----
        float s = l_;
        s += __shfl_xor(s, 16);
        s += __shfl_xor(s, 32);           // all lanes: L[query=lidx]
#pragma unroll
        for (int r = 0; r < 4; ++r) {
            float inv = __builtin_amdgcn_rcpf(__shfl(s, quad * 4 + r));
            int tok = bu * 512 + q0 + quad * 4 + r;
#pragma unroll
            for (int nt = 0; nt < 2; ++nt)
                ob[(size_t)tok * 256 + h * 32 + nt * 16 + lidx] =
                    (bf16_t)(Oacc[nt][r] * inv);
        }
    }
}

// ---------------------------------------------------------------------------
// Fused tail: out = r1 + FFN(LN2(r1)),  r1 = z + attn@Wo^T + ff_b.
// 512 threads / 32 tokens (1024 blocks -> 4 blocks/CU x 8 waves = 32
// waves/CU, 100% cap; VGPR<=64 via 32-wide n-slice per wave). One aliased
// LDS buffer [32][264]: A-tile (bf16) -> LN out (bf16) -> GELU out (bf16)
// -> final f32, flushed with fully-coalesced float4 row writes. 36.1 KB.
// ---------------------------------------------------------------------------
__global__ __launch_bounds__(512, 8) void tail_kernel(
    const bf16_t* __restrict__ X, const bf16_t* __restrict__ Wo,
    const float* __restrict__ obias, const float* __restrict__ zin,
    const float* __restrict__ ln_g, const float* __restrict__ ln_b,
    const bf16_t* __restrict__ W1, const float* __restrict__ b1,
    const bf16_t* __restrict__ W2, const float* __restrict__ b2,
    float* __restrict__ outp) {
    __shared__ float fbuf[32 * 264];   // 33.8 KB; bf16 view aliases phases
    __shared__ float red[32 * 16];     // 2 KB (8 waves x {s,ss} per row)
    __shared__ float mi[32 * 2];
    bf16_t* xbuf = (bf16_t*)fbuf;
    int tid = threadIdx.x;
    int t0 = blockIdx.x * 32;
    int wv = tid >> 6, lane = tid & 63, quad = lane >> 4, lidx = lane & 15;

    // ---- stage A (attn out tile) into LDS, coalesced ----
    {
        int row = tid >> 4;               // 0..31
        int c0 = (tid & 15) * 16;         // 0..240
        const bf16x8* src = (const bf16x8*)&X[(size_t)(t0 + row) * 256 + c0];
        bf16x8* dst = (bf16x8*)&xbuf[row * 264 + c0];
        dst[0] = src[0]; dst[1] = src[1];
    }
    __syncthreads();

    float r1[2][2][4];   // [ntl][mt][r]
    {
        floatx4 acc[2][2];
#pragma unroll
        for (int i = 0; i < 2; ++i) {
            acc[i][0] = (floatx4){0.f, 0.f, 0.f, 0.f};
            acc[i][1] = (floatx4){0.f, 0.f, 0.f, 0.f};
        }
#pragma unroll 2
        for (int kc = 0; kc < 8; ++kc) {
            bf16x8 a0 = *(const bf16x8*)&xbuf[lidx * 264 + kc * 32 + quad * 8];
            bf16x8 a1 = *(const bf16x8*)&xbuf[(16 + lidx) * 264 + kc * 32 + quad * 8];
#pragma unroll
            for (int ntl = 0; ntl < 2; ++ntl) {
                int n = wv * 32 + ntl * 16 + lidx;
                bf16x8 bfr = *(const bf16x8*)&Wo[(size_t)n * 256 + kc * 32 + quad * 8];
                acc[ntl][0] = MFMA16(a0, bfr, acc[ntl][0]);
                acc[ntl][1] = MFMA16(a1, bfr, acc[ntl][1]);
            }
        }
#pragma unroll
        for (int ntl = 0; ntl < 2; ++ntl) {
            int n = wv * 32 + ntl * 16 + lidx;
            float b = obias[n];
#pragma unroll
            for (int mt = 0; mt < 2; ++mt)
#pragma unroll
                for (int r = 0; r < 4; ++r) {
                    size_t o = (size_t)(t0 + mt * 16 + quad * 4 + r) * 256 + n;
                    r1[ntl][mt][r] = zin[o] + acc[ntl][mt][r] + b;
                }
        }
    }

    // ---- LN2 statistics (per-wave partials over its 32 n) ----
#pragma unroll
    for (int mt = 0; mt < 2; ++mt)
#pragma unroll
        for (int r = 0; r < 4; ++r) {
            float v0 = r1[0][mt][r], v1 = r1[1][mt][r];
            float s = v0 + v1;
            float ss = v0 * v0 + v1 * v1;
#pragma unroll
            for (int off = 8; off >= 1; off >>= 1) {
                s += __shfl_xor(s, off);
                ss += __shfl_xor(ss, off);
            }
            if (lidx == 0) {
                int row = mt * 16 + quad * 4 + r;
                red[row * 16 + wv * 2] = s;
                red[row * 16 + wv * 2 + 1] = ss;
            }
        }
    __syncthreads();
    if (tid < 32) {
        float s = 0.f, ss = 0.f;
#pragma unroll
        for (int w = 0; w < 8; ++w) {
            s += red[tid * 16 + w * 2];
            ss += red[tid * 16 + w * 2 + 1];
        }
        float mu = s * (1.f / 256.f);
        mi[tid * 2] = mu;
        mi[tid * 2 + 1] = rsqrtf(ss * (1.f / 256.f) - mu * mu + 1e-5f);
    }
    __syncthreads();

    // ---- LN2 apply -> xbuf (A-tile is dead, safe to overwrite) ----
    {
        float gv[2], bv[2];
#pragma unroll
        for (int ntl = 0; ntl < 2; ++ntl) {
            int n = wv * 32 + ntl * 16 + lidx;
            gv[ntl] = ln_g[n]; bv[ntl] = ln_b[n];
        }
#pragma unroll
        for (int mt = 0; mt < 2; ++mt)
#pragma unroll
            for (int r = 0; r < 4; ++r) {
                int row = mt * 16 + quad * 4 + r;
                float mu = mi[row * 2], inv = mi[row * 2 + 1];
#pragma unroll
                for (int ntl = 0; ntl < 2; ++ntl) {
                    int n = wv * 32 + ntl * 16 + lidx;
                    xbuf[row * 264 + n] =
                        (bf16_t)((r1[ntl][mt][r] - mu) * inv * gv[ntl] + bv[ntl]);
                }
            }
    }
    __syncthreads();

    // ---- W1 GEMM + GELU, result back into xbuf ----
    {
        floatx4 acc[2][2];
#pragma unroll
        for (int i = 0; i < 2; ++i) {
            acc[i][0] = (floatx4){0.f, 0.f, 0.f, 0.f};
            acc[i][1] = (floatx4){0.f, 0.f, 0.f, 0.f};
        }
#pragma unroll 2
        for (int kc = 0; kc < 8; ++kc) {
            bf16x8 a0 = *(const bf16x8*)&xbuf[lidx * 264 + kc * 32 + quad * 8];
            bf16x8 a1 = *(const bf16x8*)&xbuf[(16 + lidx) * 264 + kc * 32 + quad * 8];
#pragma unroll
            for (int ntl = 0; ntl < 2; ++ntl) {
                int n = wv * 32 + ntl * 16 + lidx;
                bf16x8 bfr = *(const bf16x8*)&W1[(size_t)n * 256 + kc * 32 + quad * 8];
                acc[ntl][0] = MFMA16(a0, bfr, acc[ntl][0]);
                acc[ntl][1] = MFMA16(a1, bfr, acc[ntl][1]);
            }
        }
        __syncthreads();   // all reads of LN-out done before overwrite
#pragma unroll
        for (int ntl = 0; ntl < 2; ++ntl) {
            int n = wv * 32 + ntl * 16 + lidx;
            float b = b1[n];
#pragma unroll
            for (int mt = 0; mt < 2; ++mt)
#pragma unroll
                for (int r = 0; r < 4; ++r) {
                    float x = acc[ntl][mt][r] + b;
                    xbuf[(mt * 16 + quad * 4 + r) * 264 + n] = (bf16_t)gelu_f(x);
                }
        }
    }
    __syncthreads();

    // ---- W2 GEMM, final residual into fbuf (f32) ----
    {
        floatx4 acc[2][2];
#pragma unroll
        for (int i = 0; i < 2; ++i) {
            acc[i][0] = (floatx4){0.f, 0.f, 0.f, 0.f};
            acc[i][1] = (floatx4){0.f, 0.f, 0.f, 0.f};
        }
#pragma unroll 2
        for (int kc = 0; kc < 8; ++kc) {
            bf16x8 a0 = *(const bf16x8*)&xbuf[lidx * 264 + kc * 32 + quad * 8];
            bf16x8 a1 = *(const bf16x8*)&xbuf[(16 + lidx) * 264 + kc * 32 + quad * 8];
#pragma unroll
            for (int ntl = 0; ntl < 2; ++ntl) {
                int n = wv * 32 + ntl * 16 + lidx;
                bf16x8 bfr = *(const bf16x8*)&W2[(size_t)n * 256 + kc * 32 + quad * 8];
                acc[ntl][0] = MFMA16(a0, bfr, acc[ntl][0]);
                acc[ntl][1] = MFMA16(a1, bfr, acc[ntl][1]);
            }
        }
        __syncthreads();   // all reads of GELU-out done before f32 overwrite
#pragma unroll
        for (int ntl = 0; ntl < 2; ++ntl) {
            int n = wv * 32 + ntl * 16 + lidx;
            float b = b2[n];
#pragma unroll
            for (int mt = 0; mt < 2; ++mt)
#pragma unroll
                for (int r = 0; r < 4; ++r)
                    fbuf[(mt * 16 + quad * 4 + r) * 264 + n] =
                        r1[ntl][mt][r] + acc[ntl][mt][r] + b;
        }
    }
    __syncthreads();

    // ---- coalesced flush: full 1 KB rows, float4 per lane ----
#pragma unroll
    for (int i = 0; i < 4; ++i) {
        int fid = i * 512 + tid;
        int row = fid >> 6;
        int c4 = (fid & 63) * 4;
        *(floatx4*)&outp[(size_t)(t0 + row) * 256 + c4] =
            *(const floatx4*)&fbuf[row * 264 + c4];
    }
}

// ---------------------------------------------------------------------------
extern "C" void kernel_launch(void* const* d_in, const int* in_sizes, int n_in,
                              void* d_out, int out_size, void* d_ws, size_t ws_size,
                              hipStream_t stream) {
    const float* z      = (const float*)d_in[0];
    const float* ln1_g  = (const float*)d_in[1];
    const float* ln1_b  = (const float*)d_in[2];
    const float* proj_v = (const float*)d_in[3];
    const float* proj_g = (const float*)d_in[4];
    const float* proj_b = (const float*)d_in[5];
    const float* ff_v   = (const float*)d_in[6];
    const float* ff_g   = (const float*)d_in[7];
    const float* ff_b   = (const float*)d_in[8];
    const float* ln2_g  = (const float*)d_in[9];
    const float* ln2_b  = (const float*)d_in[10];
    const float* w1_v   = (const float*)d_in[11];
    const float* w1_g   = (const float*)d_in[12];
    const float* w1_b   = (const float*)d_in[13];
    const float* w2_v   = (const float*)d_in[14];
    const float* w2_g   = (const float*)d_in[15];
    const float* w2_b   = (const float*)d_in[16];
    float* out = (float*)d_out;

    char* p = (char*)d_ws;
    bf16_t* Wall = (bf16_t*)p; p += (size_t)1536 * 256 * 2;
    float* ctab  = (float*)p;  p += 8192 * 4;
    float* stab  = (float*)p;  p += 8192 * 4;
    // q/k: [bh][a][d]; vtb: [bh][d][a]; each 512*512*32 = TOK*256 elems
    bf16_t* qbf  = (bf16_t*)p; p += (size_t)TOK * 256 * 2;
    bf16_t* kbf  = (bf16_t*)p; p += (size_t)TOK * 256 * 2;
    bf16_t* vtb  = (bf16_t*)p; p += (size_t)TOK * 256 * 2;
    bf16_t* abuf = (bf16_t*)p; p += (size_t)TOK * 256 * 2;

    const bf16_t* Wqkv = Wall;
    const bf16_t* Wo   = Wall + (size_t)768 * 256;
    const bf16_t* W1   = Wall + (size_t)1024 * 256;
    const bf16_t* W2   = Wall + (size_t)1280 * 256;

    setup_kernel<<<1664, 64, 0, stream>>>(proj_v, proj_g, ff_v, ff_g,
                                          w1_v, w1_g, w2_v, w2_g,
                                          Wall, ctab, stab);
    qkv_kernel<<<TOK / 32, 256, 0, stream>>>(z, ln1_g, ln1_b, Wqkv, proj_b,
                                             ctab, stab, qbf, kbf, vtb);
    attn_kernel<<<64 * 8, 512, 0, stream>>>(qbf, kbf, vtb, abuf);
    tail_kernel<<<TOK / 32, 512, 0, stream>>>(abuf, Wo, ff_b, z, ln2_g, ln2_b,
                                              W1, w1_b, W2, w2_b, out);
}

// Round 7
// 252.160 us; speedup vs baseline: 1.0234x; 1.0234x over previous
//
#include <hip/hip_runtime.h>
#include <cmath>

#define EMB 256
#define NHEAD 8
#define HD 32
#define A_LEN 512
#define TOK 32768

typedef __bf16 bf16_t;
typedef __bf16 bf16x8 __attribute__((ext_vector_type(8)));
typedef __bf16 bf16x4 __attribute__((ext_vector_type(4)));
typedef float floatx4 __attribute__((ext_vector_type(4)));

#define MFMA16(a, b, c) __builtin_amdgcn_mfma_f32_16x16x32_bf16((a), (b), (c), 0, 0, 0)

// Fast exact-gelu: erf via Abramowitz-Stegun 7.1.26 (|err|<1.5e-7, far below
// bf16 storage rounding). ~12 VALU + 1 exp vs ~30 for libm erff.
__device__ __forceinline__ float gelu_f(float x) {
    float ax = fabsf(x) * 0.7071067811865476f;
    float t = __builtin_amdgcn_rcpf(fmaf(0.3275911f, ax, 1.0f));
    float poly = t * fmaf(t, fmaf(t, fmaf(t, fmaf(t, 1.061405429f, -1.453152027f),
                          1.421413741f), -0.284496736f), 0.254829592f);
    float erfv = 1.0f - poly * __expf(-ax * ax);
    erfv = copysignf(erfv, x);
    return 0.5f * x * (1.0f + erfv);
}

// ---------------------------------------------------------------------------
// Setup: weight_norm all 4 weights -> bf16 rows in Wall, plus RoPE cos/sin
// tables. Blocks 0..1535: one wave per weight row. Blocks 1536..1663: table.
// ---------------------------------------------------------------------------
__global__ __launch_bounds__(64) void setup_kernel(
    const float* __restrict__ proj_v, const float* __restrict__ proj_g,
    const float* __restrict__ ff_v, const float* __restrict__ ff_g,
    const float* __restrict__ w1_v, const float* __restrict__ w1_g,
    const float* __restrict__ w2_v, const float* __restrict__ w2_g,
    bf16_t* __restrict__ Wall, float* __restrict__ ctab,
    float* __restrict__ stab) {
    int b = blockIdx.x;
    int lane = threadIdx.x;
    if (b < 1536) {
        const float* v; const float* g; int r;
        if (b < 768)       { v = proj_v; g = proj_g; r = b; }
        else if (b < 1024) { v = ff_v;   g = ff_g;   r = b - 768; }
        else if (b < 1280) { v = w1_v;   g = w1_g;   r = b - 1024; }
        else               { v = w2_v;   g = w2_g;   r = b - 1280; }
        const floatx4* vr = (const floatx4*)(v + (size_t)r * 256);
        floatx4 x = vr[lane];
        float ss = x[0] * x[0] + x[1] * x[1] + x[2] * x[2] + x[3] * x[3];
#pragma unroll
        for (int off = 32; off >= 1; off >>= 1) ss += __shfl_xor(ss, off);
        float sc = g[r] * rsqrtf(ss);
        bf16x4 o;
        o[0] = (bf16_t)(x[0] * sc); o[1] = (bf16_t)(x[1] * sc);
        o[2] = (bf16_t)(x[2] * sc); o[3] = (bf16_t)(x[3] * sc);
        ((bf16x4*)(Wall + (size_t)b * 256))[lane] = o;
    } else {
        int idx = (b - 1536) * 64 + lane;     // 0..8191 = a*16 + i
        int a = idx >> 4, i = idx & 15;
        float freq = expf(-(float)(2 * i) * 0.2878231366242558f); // ln(1e4)/32
        float ang = (float)a * freq;
        ctab[idx] = cosf(ang);
        stab[idx] = sinf(ang);
    }
}

// ---------------------------------------------------------------------------
// QKV: 32 tokens/block (1024 blocks -> 4 blocks/CU). LN1 -> bf16 xns (LDS).
// q/k sections: W as MFMA *A*-operand so each lane's 4 acc regs are 4
// CONSECUTIVE output dims of one token -> RoPE pairs are in-lane (no
// shuffles, float2 table loads, single f32 rounding). Bias folded into
// MFMA C-init. Results staged in LDS [32][264] and flushed with 16B/lane
// fully-coalesced stores. v keeps transposed staging -> [bh][d][a].
// LDS 16.9 + 17.0 = 33.9 KB -> 4 blocks/CU.
// ---------------------------------------------------------------------------
__global__ __launch_bounds__(256, 4) void qkv_kernel(
    const float* __restrict__ z, const float* __restrict__ ln_g,
    const float* __restrict__ ln_b, const bf16_t* __restrict__ W,
    const float* __restrict__ pb, const float* __restrict__ ctab,
    const float* __restrict__ stab, bf16_t* __restrict__ qbf,
    bf16_t* __restrict__ kbf, bf16_t* __restrict__ vtb) {
    __shared__ bf16_t xns[32 * 264];   // 16.9 KB
    __shared__ bf16_t stg[8704];       // 17.0 KB (q/k: [32][264]; v: [256][34])
    int tid = threadIdx.x;
    int t0 = blockIdx.x * 32;
    int bu = t0 >> 9, a0 = t0 & 511;

    // ---- LN1 -> xns ----
#pragma unroll
    for (int it = 0; it < 2; ++it) {
        int row = it * 16 + (tid >> 4);
        int sub = tid & 15;
        const floatx4* zr = (const floatx4*)(z + (size_t)(t0 + row) * 256 + sub * 16);
        floatx4 v0 = zr[0], v1 = zr[1], v2 = zr[2], v3 = zr[3];
        float vals[16];
        ((floatx4*)vals)[0] = v0; ((floatx4*)vals)[1] = v1;
        ((floatx4*)vals)[2] = v2; ((floatx4*)vals)[3] = v3;
        float s = 0.f, q2 = 0.f;
#pragma unroll
        for (int i = 0; i < 16; ++i) { s += vals[i]; q2 += vals[i] * vals[i]; }
#pragma unroll
        for (int off = 8; off >= 1; off >>= 1) {
            s += __shfl_xor(s, off);
            q2 += __shfl_xor(q2, off);
        }
        float mu = s * (1.f / 256.f);
        float inv = rsqrtf(q2 * (1.f / 256.f) - mu * mu + 1e-5f);
        int cb = sub * 16;
        bf16x8 o0, o1;
#pragma unroll
        for (int i = 0; i < 8; ++i)
            o0[i] = (bf16_t)((vals[i] - mu) * inv * ln_g[cb + i] + ln_b[cb + i]);
#pragma unroll
        for (int i = 0; i < 8; ++i)
            o1[i] = (bf16_t)((vals[8 + i] - mu) * inv * ln_g[cb + 8 + i] + ln_b[cb + 8 + i]);
        *(bf16x8*)&xns[row * 264 + cb] = o0;
        *(bf16x8*)&xns[row * 264 + cb + 8] = o1;
    }
    __syncthreads();

    int wv = tid >> 6, lane = tid & 63, quad = lane >> 4, lidx = lane & 15;

    // ---- q/k sections (sec 0 = q, 1 = k): W rows as A-operand ----
#pragma unroll 1
    for (int sec = 0; sec < 2; ++sec) {
        bf16_t* __restrict__ dst = (sec == 0) ? qbf : kbf;
        floatx4 acc[4][2];
#pragma unroll
        for (int ntl = 0; ntl < 4; ++ntl) {
            int cb = wv * 64 + ntl * 16;           // within-sec column base
            int ht = cb >> 5;
            floatx4 b4 = *(const floatx4*)&pb[ht * 96 + sec * 32 + (cb & 31) + quad * 4];
            acc[ntl][0] = b4; acc[ntl][1] = b4;
        }
#pragma unroll 2
        for (int kc = 0; kc < 8; ++kc) {
            bf16x8 x0 = *(const bf16x8*)&xns[lidx * 264 + kc * 32 + quad * 8];
            bf16x8 x1 = *(const bf16x8*)&xns[(16 + lidx) * 264 + kc * 32 + quad * 8];
#pragma unroll
            for (int ntl = 0; ntl < 4; ++ntl) {
                int cb = wv * 64 + ntl * 16;
                int ht = cb >> 5;
                int n = ht * 96 + sec * 32 + (cb & 31) + lidx;
                bf16x8 wf = *(const bf16x8*)&W[(size_t)n * 256 + kc * 32 + quad * 8];
                acc[ntl][0] = MFMA16(wf, x0, acc[ntl][0]);
                acc[ntl][1] = MFMA16(wf, x1, acc[ntl][1]);
            }
        }
        // RoPE in-lane (acc regs r=0..3 are consecutive d), stage to LDS
        float scl = (sec == 0) ? 0.17677669529663687f : 1.0f;
#pragma unroll
        for (int ntl = 0; ntl < 4; ++ntl) {
            int cb = wv * 64 + ntl * 16;
            int d0 = (cb & 31) + quad * 4;         // multiple of 4
            int fi = d0 >> 1;                      // even, <= 14
#pragma unroll
            for (int tt = 0; tt < 2; ++tt) {
                int al = tt * 16 + lidx;
                int a = a0 + al;
                float cs0 = ctab[a * 16 + fi],     cs1 = ctab[a * 16 + fi + 1];
                float sn0 = stab[a * 16 + fi],     sn1 = stab[a * 16 + fi + 1];
                floatx4 v = acc[ntl][tt];
                bf16x4 o;
                o[0] = (bf16_t)((v[0] * cs0 - v[1] * sn0) * scl);
                o[1] = (bf16_t)((v[1] * cs0 + v[0] * sn0) * scl);
                o[2] = (bf16_t)((v[2] * cs1 - v[3] * sn1) * scl);
                o[3] = (bf16_t)((v[3] * cs1 + v[2] * sn1) * scl);
                *(bf16x4*)&stg[al * 264 + cb + quad * 4] = o;
            }
        }
        __syncthreads();
        // coalesced flush: 1024 x 16B chunks; wave writes 1KB contiguous
#pragma unroll
        for (int i = 0; i < 4; ++i) {
            int cid = i * 256 + tid;
            int chunk = cid & 3, al = (cid >> 2) & 31, ht = cid >> 7;
            bf16x8 vv = *(const bf16x8*)&stg[al * 264 + ht * 32 + chunk * 8];
            *(bf16x8*)&dst[((size_t)((bu * 8 + ht) * 512 + a0 + al)) * 32 + chunk * 8] = vv;
        }
        __syncthreads();
    }

    // ---- v section: X as A-operand; stage transposed [vcol][a_loc] ----
    {
        floatx4 acc[4][2];
#pragma unroll
        for (int ntl = 0; ntl < 4; ++ntl) {
            int cb = wv * 64 + ntl * 16;
            int ht = cb >> 5;
            float b = pb[ht * 96 + 64 + (cb & 31) + lidx];
            acc[ntl][0] = (floatx4){b, b, b, b};
            acc[ntl][1] = (floatx4){b, b, b, b};
        }
#pragma unroll 2
        for (int kc = 0; kc < 8; ++kc) {
            bf16x8 x0 = *(const bf16x8*)&xns[lidx * 264 + kc * 32 + quad * 8];
            bf16x8 x1 = *(const bf16x8*)&xns[(16 + lidx) * 264 + kc * 32 + quad * 8];
#pragma unroll
            for (int ntl = 0; ntl < 4; ++ntl) {
                int cb = wv * 64 + ntl * 16;
                int ht = cb >> 5;
                int n = ht * 96 + 64 + (cb & 31) + lidx;
                bf16x8 wf = *(const bf16x8*)&W[(size_t)n * 256 + kc * 32 + quad * 8];
                acc[ntl][0] = MFMA16(x0, wf, acc[ntl][0]);
                acc[ntl][1] = MFMA16(x1, wf, acc[ntl][1]);
            }
        }
#pragma unroll
        for (int ntl = 0; ntl < 4; ++ntl) {
            int vcol = wv * 64 + ntl * 16 + lidx;
#pragma unroll
            for (int tt = 0; tt < 2; ++tt)
#pragma unroll
                for (int r = 0; r < 4; ++r)
                    stg[vcol * 34 + tt * 16 + quad * 4 + r] = (bf16_t)acc[ntl][tt][r];
        }
        __syncthreads();
#pragma unroll
        for (int i = 0; i < 4; ++i) {
            int cid = i * 256 + tid;
            int chunk = cid & 3, vcol = cid >> 2;
            bf16x8 vv = *(const bf16x8*)&stg[vcol * 34 + chunk * 8];
            *(bf16x8*)&vtb[((size_t)(bu * 256 + vcol)) * 512 + a0 + chunk * 8] = vv;
        }
    }
}

// ---------------------------------------------------------------------------
// Attention: one block (512 thr = 8 waves) per (bu,h). Swapped QK^T
// (mfma(K,Q)) + permuted K-row feed so each lane's 16 exp'd scores ARE the
// PV A-fragment in-lane: zero P LDS traffic, zero cross-lane P exchange.
// Row-sums accumulate in-lane (query = lidx); 2-shuffle reduce + 4 shfl
// redistribution per q-tile. exp(s-8) via MFMA C-init (shift-invariant).
// All arrays loop-local & statically indexed (no scratch). LDS 64 KB.
// ---------------------------------------------------------------------------
__global__ __launch_bounds__(512, 4) void attn_kernel(
    const bf16_t* __restrict__ qbf, const bf16_t* __restrict__ kbf,
    const bf16_t* __restrict__ vtb, bf16_t* __restrict__ ob) {
    __shared__ bf16_t Kls[512 * 32];      // 32 KB
    __shared__ bf16_t Vt[32 * 512];       // 32 KB
    int tid = threadIdx.x;
    int wv = tid >> 6, lane = tid & 63, quad = lane >> 4, lidx = lane & 15;
    int bh = blockIdx.x;
    int bu = bh >> 3, h = bh & 7;
    size_t hb = (size_t)bh * (A_LEN * HD);

    // ---- stage K (row-swizzled) and V^T (pre-transposed in global) ----
#pragma unroll
    for (int i = 0; i < 4; ++i) {
        int c = tid + i * 512;            // 16B chunk id, 0..2047
        int key = c >> 2, blk = c & 3;
        bf16x8 kv = *(const bf16x8*)&kbf[hb + (size_t)c * 8];
        *(bf16x8*)&Kls[key * 32 + ((blk ^ (key & 3)) << 3)] = kv;
        int vrow = c >> 6, vblk = c & 63;
        bf16x8 vv = *(const bf16x8*)&vtb[hb + (size_t)c * 8];
        *(bf16x8*)&Vt[vrow * 512 + ((vblk ^ (vrow & 7)) << 3)] = vv;
    }
    __syncthreads();

    const floatx4 cm8 = (floatx4){-8.f, -8.f, -8.f, -8.f};
    const floatx4 zero4 = (floatx4){0.f, 0.f, 0.f, 0.f};
    // permuted K-row base within a 64-key block (t adds (t&1)*4 + (t>>1)*32)
    int krow = ((lidx >> 2) << 3) + (lidx & 3);
    int kswz = (quad ^ (lidx & 3)) << 3;

#pragma unroll 1
    for (int mt = 0; mt < 4; ++mt) {
        int q0 = wv * 64 + mt * 16;
        // Q fragment: content valid as B-operand (same lane layout as A)
        bf16x8 qfrag = *(const bf16x8*)&qbf[hb + (size_t)(q0 + lidx) * 32 + quad * 8];
        float l_ = 0.f;
        floatx4 Oacc[2];
        Oacc[0] = zero4; Oacc[1] = zero4;

#pragma unroll 1
        for (int kc = 0; kc < 8; ++kc) {
            // QK^T swapped: D[key][query]; lane holds query=lidx,
            // keys = quad*8 + (t&1)*4 + j + (t>>1)*32 (via permuted row feed)
            floatx4 sc[4];
#pragma unroll
            for (int t = 0; t < 4; ++t) {
                int row = kc * 64 + (t >> 1) * 32 + ((t & 1) << 2) + krow;
                bf16x8 kf = *(const bf16x8*)&Kls[row * 32 + kswz];
                sc[t] = MFMA16(kf, qfrag, cm8);   // s - 8 folded into C
            }
            float p[4][4];
#pragma unroll
            for (int t = 0; t < 4; ++t)
#pragma unroll
                for (int r = 0; r < 4; ++r) p[t][r] = __expf(sc[t][r]);
            // in-lane row-sum partial (query = lidx)
#pragma unroll
            for (int t = 0; t < 4; ++t)
                l_ += (p[t][0] + p[t][1]) + (p[t][2] + p[t][3]);
            // pack P directly as PV A-fragments (all in-lane)
            bf16x8 pa0, pa1;
#pragma unroll
            for (int r = 0; r < 4; ++r) {
                pa0[r]     = (bf16_t)p[0][r];
                pa0[4 + r] = (bf16_t)p[1][r];
                pa1[r]     = (bf16_t)p[2][r];
                pa1[4 + r] = (bf16_t)p[3][r];
            }
            // PV
#pragma unroll
            for (int nt = 0; nt < 2; ++nt) {
                int vr = nt * 16 + lidx;
                bf16x8 vf0 = *(const bf16x8*)&Vt[vr * 512 +
                    ((kc * 8 + ((0 * 4 + quad) ^ (lidx & 7))) << 3)];
                Oacc[nt] = MFMA16(pa0, vf0, Oacc[nt]);
                bf16x8 vf1 = *(const bf16x8*)&Vt[vr * 512 +
                    ((kc * 8 + ((1 * 4 + quad) ^ (lidx & 7))) << 3)];
                Oacc[nt] = MFMA16(pa1, vf1, Oacc[nt]);
            }
        }

        // ---- epilogue: reduce L across quads, redistribute, store ----
        float s = l_;
        s += __shfl_xor(s, 16);
        s += __shfl_xor(s, 32);           // all lanes: L[query=lidx]
#pragma unroll
        for (int r = 0; r < 4; ++r) {
            float inv = __builtin_amdgcn_rcpf(__shfl(s, quad * 4 + r));
            int tok = bu * 512 + q0 + quad * 4 + r;
#pragma unroll
            for (int nt = 0; nt < 2; ++nt)
                ob[(size_t)tok * 256 + h * 32 + nt * 16 + lidx] =
                    (bf16_t)(Oacc[nt][r] * inv);
        }
    }
}

// ---------------------------------------------------------------------------
// Fused tail: out = r1 + FFN(LN2(r1)),  r1 = z + attn@Wo^T + ff_b.
// 512 threads / 32 tokens (1024 blocks). r1 lives in LDS fbuf (f32, stride
// 260 = 2-lanes/bank free) -> register peak ~45 VGPR, spill impossible
// (round-6 lesson: r1-in-regs under (512,8) spilled to scratch, +53 MB HBM).
// xbuf (bf16, separate) carries A-tile -> LN-out -> GELU-out. fbuf is
// updated in place to the final f32 result and flushed coalesced.
// LDS 52.4 KB -> 3 blocks/CU x 8 waves = 24 waves/CU.
// ---------------------------------------------------------------------------
__global__ __launch_bounds__(512, 4) void tail_kernel(
    const bf16_t* __restrict__ X, const bf16_t* __restrict__ Wo,
    const float* __restrict__ obias, const float* __restrict__ zin,
    const float* __restrict__ ln_g, const float* __restrict__ ln_b,
    const bf16_t* __restrict__ W1, const float* __restrict__ b1,
    const bf16_t* __restrict__ W2, const float* __restrict__ b2,
    float* __restrict__ outp) {
    __shared__ float fbuf[32 * 260];   // 33.3 KB: r1 -> final f32 result
    __shared__ bf16_t xbuf[32 * 264];  // 16.9 KB: A-tile -> LN-out -> GELU-out
    __shared__ float red[32 * 16];     // 2 KB (8 waves x {s,ss} per row)
    __shared__ float mi[32 * 2];
    int tid = threadIdx.x;
    int t0 = blockIdx.x * 32;
    int wv = tid >> 6, lane = tid & 63, quad = lane >> 4, lidx = lane & 15;
    int n0 = wv * 32 + lidx, n1 = wv * 32 + 16 + lidx;

    // ---- stage A (attn out tile) into LDS, coalesced ----
    {
        int row = tid >> 4;               // 0..31
        int c0 = (tid & 15) * 16;         // 0..240
        const bf16x8* src = (const bf16x8*)&X[(size_t)(t0 + row) * 256 + c0];
        bf16x8* dst = (bf16x8*)&xbuf[row * 264 + c0];
        dst[0] = src[0]; dst[1] = src[1];
    }
    __syncthreads();

    // ---- Wo GEMM -> r1 into fbuf (f32) + LN2 stats partials ----
    {
        floatx4 acc[2][2];
#pragma unroll
        for (int i = 0; i < 2; ++i) {
            acc[i][0] = (floatx4){0.f, 0.f, 0.f, 0.f};
            acc[i][1] = (floatx4){0.f, 0.f, 0.f, 0.f};
        }
#pragma unroll 2
        for (int kc = 0; kc < 8; ++kc) {
            bf16x8 a0 = *(const bf16x8*)&xbuf[lidx * 264 + kc * 32 + quad * 8];
            bf16x8 a1 = *(const bf16x8*)&xbuf[(16 + lidx) * 264 + kc * 32 + quad * 8];
#pragma unroll
            for (int ntl = 0; ntl < 2; ++ntl) {
                int n = wv * 32 + ntl * 16 + lidx;
                bf16x8 bfr = *(const bf16x8*)&Wo[(size_t)n * 256 + kc * 32 + quad * 8];
                acc[ntl][0] = MFMA16(a0, bfr, acc[ntl][0]);
                acc[ntl][1] = MFMA16(a1, bfr, acc[ntl][1]);
            }
        }
        float ob0 = obias[n0], ob1 = obias[n1];
#pragma unroll
        for (int mt = 0; mt < 2; ++mt)
#pragma unroll
            for (int r = 0; r < 4; ++r) {
                int row = mt * 16 + quad * 4 + r;
                size_t zo = (size_t)(t0 + row) * 256;
                float v0 = zin[zo + n0] + acc[0][mt][r] + ob0;
                float v1 = zin[zo + n1] + acc[1][mt][r] + ob1;
                fbuf[row * 260 + n0] = v0;
                fbuf[row * 260 + n1] = v1;
                float s = v0 + v1;
                float ss = v0 * v0 + v1 * v1;
#pragma unroll
                for (int off = 8; off >= 1; off >>= 1) {
                    s += __shfl_xor(s, off);
                    ss += __shfl_xor(ss, off);
                }
                if (lidx == 0) {
                    red[row * 16 + wv * 2] = s;
                    red[row * 16 + wv * 2 + 1] = ss;
                }
            }
    }
    __syncthreads();
    if (tid < 32) {
        float s = 0.f, ss = 0.f;
#pragma unroll
        for (int w = 0; w < 8; ++w) {
            s += red[tid * 16 + w * 2];
            ss += red[tid * 16 + w * 2 + 1];
        }
        float mu = s * (1.f / 256.f);
        mi[tid * 2] = mu;
        mi[tid * 2 + 1] = rsqrtf(ss * (1.f / 256.f) - mu * mu + 1e-5f);
    }
    __syncthreads();

    // ---- LN2 apply: read own r1 from fbuf -> xbuf (A-tile dead) ----
    {
        float gv0 = ln_g[n0], bv0 = ln_b[n0];
        float gv1 = ln_g[n1], bv1 = ln_b[n1];
#pragma unroll
        for (int mt = 0; mt < 2; ++mt)
#pragma unroll
            for (int r = 0; r < 4; ++r) {
                int row = mt * 16 + quad * 4 + r;
                float mu = mi[row * 2], inv = mi[row * 2 + 1];
                float v0 = fbuf[row * 260 + n0];
                float v1 = fbuf[row * 260 + n1];
                xbuf[row * 264 + n0] = (bf16_t)((v0 - mu) * inv * gv0 + bv0);
                xbuf[row * 264 + n1] = (bf16_t)((v1 - mu) * inv * gv1 + bv1);
            }
    }
    __syncthreads();

    // ---- W1 GEMM + GELU, result back into xbuf ----
    {
        floatx4 acc[2][2];
#pragma unroll
        for (int i = 0; i < 2; ++i) {
            acc[i][0] = (floatx4){0.f, 0.f, 0.f, 0.f};
            acc[i][1] = (floatx4){0.f, 0.f, 0.f, 0.f};
        }
#pragma unroll 2
        for (int kc = 0; kc < 8; ++kc) {
            bf16x8 a0 = *(const bf16x8*)&xbuf[lidx * 264 + kc * 32 + quad * 8];
            bf16x8 a1 = *(const bf16x8*)&xbuf[(16 + lidx) * 264 + kc * 32 + quad * 8];
#pragma unroll
            for (int ntl = 0; ntl < 2; ++ntl) {
                int n = wv * 32 + ntl * 16 + lidx;
                bf16x8 bfr = *(const bf16x8*)&W1[(size_t)n * 256 + kc * 32 + quad * 8];
                acc[ntl][0] = MFMA16(a0, bfr, acc[ntl][0]);
                acc[ntl][1] = MFMA16(a1, bfr, acc[ntl][1]);
            }
        }
        __syncthreads();   // all reads of LN-out done before overwrite
        float b10 = b1[n0], b11 = b1[n1];
#pragma unroll
        for (int mt = 0; mt < 2; ++mt)
#pragma unroll
            for (int r = 0; r < 4; ++r) {
                int row = mt * 16 + quad * 4 + r;
                xbuf[row * 264 + n0] = (bf16_t)gelu_f(acc[0][mt][r] + b10);
                xbuf[row * 264 + n1] = (bf16_t)gelu_f(acc[1][mt][r] + b11);
            }
    }
    __syncthreads();

    // ---- W2 GEMM, final residual: fbuf += acc + b2 (own slots) ----
    {
        floatx4 acc[2][2];
#pragma unroll
        for (int i = 0; i < 2; ++i) {
            acc[i][0] = (floatx4){0.f, 0.f, 0.f, 0.f};
            acc[i][1] = (floatx4){0.f, 0.f, 0.f, 0.f};
        }
#pragma unroll 2
        for (int kc = 0; kc < 8; ++kc) {
            bf16x8 a0 = *(const bf16x8*)&xbuf[lidx * 264 + kc * 32 + quad * 8];
            bf16x8 a1 = *(const bf16x8*)&xbuf[(16 + lidx) * 264 + kc * 32 + quad * 8];
#pragma unroll
            for (int ntl = 0; ntl < 2; ++ntl) {
                int n = wv * 32 + ntl * 16 + lidx;
                bf16x8 bfr = *(const bf16x8*)&W2[(size_t)n * 256 + kc * 32 + quad * 8];
                acc[ntl][0] = MFMA16(a0, bfr, acc[ntl][0]);
                acc[ntl][1] = MFMA16(a1, bfr, acc[ntl][1]);
            }
        }
        float b20 = b2[n0], b21 = b2[n1];
#pragma unroll
        for (int mt = 0; mt < 2; ++mt)
#pragma unroll
            for (int r = 0; r < 4; ++r) {
                int row = mt * 16 + quad * 4 + r;
                fbuf[row * 260 + n0] += acc[0][mt][r] + b20;
                fbuf[row * 260 + n1] += acc[1][mt][r] + b21;
            }
    }
    __syncthreads();

    // ---- coalesced flush: full 1 KB rows, float4 per lane ----
#pragma unroll
    for (int i = 0; i < 4; ++i) {
        int fid = i * 512 + tid;
        int row = fid >> 6;
        int c4 = (fid & 63) * 4;
        *(floatx4*)&outp[(size_t)(t0 + row) * 256 + c4] =
            *(const floatx4*)&fbuf[row * 260 + c4];
    }
}

// ---------------------------------------------------------------------------
extern "C" void kernel_launch(void* const* d_in, const int* in_sizes, int n_in,
                              void* d_out, int out_size, void* d_ws, size_t ws_size,
                              hipStream_t stream) {
    const float* z      = (const float*)d_in[0];
    const float* ln1_g  = (const float*)d_in[1];
    const float* ln1_b  = (const float*)d_in[2];
    const float* proj_v = (const float*)d_in[3];
    const float* proj_g = (const float*)d_in[4];
    const float* proj_b = (const float*)d_in[5];
    const float* ff_v   = (const float*)d_in[6];
    const float* ff_g   = (const float*)d_in[7];
    const float* ff_b   = (const float*)d_in[8];
    const float* ln2_g  = (const float*)d_in[9];
    const float* ln2_b  = (const float*)d_in[10];
    const float* w1_v   = (const float*)d_in[11];
    const float* w1_g   = (const float*)d_in[12];
    const float* w1_b   = (const float*)d_in[13];
    const float* w2_v   = (const float*)d_in[14];
    const float* w2_g   = (const float*)d_in[15];
    const float* w2_b   = (const float*)d_in[16];
    float* out = (float*)d_out;

    char* p = (char*)d_ws;
    bf16_t* Wall = (bf16_t*)p; p += (size_t)1536 * 256 * 2;
    float* ctab  = (float*)p;  p += 8192 * 4;
    float* stab  = (float*)p;  p += 8192 * 4;
    // q/k: [bh][a][d]; vtb: [bh][d][a]; each 512*512*32 = TOK*256 elems
    bf16_t* qbf  = (bf16_t*)p; p += (size_t)TOK * 256 * 2;
    bf16_t* kbf  = (bf16_t*)p; p += (size_t)TOK * 256 * 2;
    bf16_t* vtb  = (bf16_t*)p; p += (size_t)TOK * 256 * 2;
    bf16_t* abuf = (bf16_t*)p; p += (size_t)TOK * 256 * 2;

    const bf16_t* Wqkv = Wall;
    const bf16_t* Wo   = Wall + (size_t)768 * 256;
    const bf16_t* W1   = Wall + (size_t)1024 * 256;
    const bf16_t* W2   = Wall + (size_t)1280 * 256;

    setup_kernel<<<1664, 64, 0, stream>>>(proj_v, proj_g, ff_v, ff_g,
                                          w1_v, w1_g, w2_v, w2_g,
                                          Wall, ctab, stab);
    qkv_kernel<<<TOK / 32, 256, 0, stream>>>(z, ln1_g, ln1_b, Wqkv, proj_b,
                                             ctab, stab, qbf, kbf, vtb);
    attn_kernel<<<64 * 8, 512, 0, stream>>>(qbf, kbf, vtb, abuf);
    tail_kernel<<<TOK / 32, 512, 0, stream>>>(abuf, Wo, ff_b, z, ln2_g, ln2_b,
                                              W1, w1_b, W2, w2_b, out);
}

// Round 8
// 245.041 us; speedup vs baseline: 1.0531x; 1.0291x over previous
//
#include <hip/hip_runtime.h>
#include <cmath>

#define EMB 256
#define NHEAD 8
#define HD 32
#define A_LEN 512
#define TOK 32768

typedef __bf16 bf16_t;
typedef __bf16 bf16x8 __attribute__((ext_vector_type(8)));
typedef __bf16 bf16x4 __attribute__((ext_vector_type(4)));
typedef float floatx4 __attribute__((ext_vector_type(4)));

#define MFMA16(a, b, c) __builtin_amdgcn_mfma_f32_16x16x32_bf16((a), (b), (c), 0, 0, 0)

// Fast exact-gelu: erf via Abramowitz-Stegun 7.1.26 (|err|<1.5e-7, far below
// bf16 storage rounding). ~12 VALU + 1 exp vs ~30 for libm erff.
__device__ __forceinline__ float gelu_f(float x) {
    float ax = fabsf(x) * 0.7071067811865476f;
    float t = __builtin_amdgcn_rcpf(fmaf(0.3275911f, ax, 1.0f));
    float poly = t * fmaf(t, fmaf(t, fmaf(t, fmaf(t, 1.061405429f, -1.453152027f),
                          1.421413741f), -0.284496736f), 0.254829592f);
    float erfv = 1.0f - poly * __expf(-ax * ax);
    erfv = copysignf(erfv, x);
    return 0.5f * x * (1.0f + erfv);
}

// ---------------------------------------------------------------------------
// Setup: weight_norm all 4 weights -> bf16 rows in Wall, plus RoPE cos/sin
// tables. Blocks 0..1535: one wave per weight row. Blocks 1536..1663: table.
// ---------------------------------------------------------------------------
__global__ __launch_bounds__(64) void setup_kernel(
    const float* __restrict__ proj_v, const float* __restrict__ proj_g,
    const float* __restrict__ ff_v, const float* __restrict__ ff_g,
    const float* __restrict__ w1_v, const float* __restrict__ w1_g,
    const float* __restrict__ w2_v, const float* __restrict__ w2_g,
    bf16_t* __restrict__ Wall, float* __restrict__ ctab,
    float* __restrict__ stab) {
    int b = blockIdx.x;
    int lane = threadIdx.x;
    if (b < 1536) {
        const float* v; const float* g; int r;
        if (b < 768)       { v = proj_v; g = proj_g; r = b; }
        else if (b < 1024) { v = ff_v;   g = ff_g;   r = b - 768; }
        else if (b < 1280) { v = w1_v;   g = w1_g;   r = b - 1024; }
        else               { v = w2_v;   g = w2_g;   r = b - 1280; }
        const floatx4* vr = (const floatx4*)(v + (size_t)r * 256);
        floatx4 x = vr[lane];
        float ss = x[0] * x[0] + x[1] * x[1] + x[2] * x[2] + x[3] * x[3];
#pragma unroll
        for (int off = 32; off >= 1; off >>= 1) ss += __shfl_xor(ss, off);
        float sc = g[r] * rsqrtf(ss);
        bf16x4 o;
        o[0] = (bf16_t)(x[0] * sc); o[1] = (bf16_t)(x[1] * sc);
        o[2] = (bf16_t)(x[2] * sc); o[3] = (bf16_t)(x[3] * sc);
        ((bf16x4*)(Wall + (size_t)b * 256))[lane] = o;
    } else {
        int idx = (b - 1536) * 64 + lane;     // 0..8191 = a*16 + i
        int a = idx >> 4, i = idx & 15;
        float freq = expf(-(float)(2 * i) * 0.2878231366242558f); // ln(1e4)/32
        float ang = (float)a * freq;
        ctab[idx] = cosf(ang);
        stab[idx] = sinf(ang);
    }
}

// ---------------------------------------------------------------------------
// QKV: 32 tokens/block (1024 blocks -> 4 blocks/CU). LN1 -> bf16 xns (LDS).
// q/k sections: W as MFMA *A*-operand so each lane's 4 acc regs are 4
// CONSECUTIVE output dims of one token -> RoPE pairs are in-lane (no
// shuffles, float2 table loads, single f32 rounding). Bias folded into
// MFMA C-init. Results staged in LDS [32][264] and flushed with 16B/lane
// fully-coalesced stores. v keeps transposed staging -> [bh][d][a].
// LDS 16.9 + 17.0 = 33.9 KB -> 4 blocks/CU.
// ---------------------------------------------------------------------------
__global__ __launch_bounds__(256, 4) void qkv_kernel(
    const float* __restrict__ z, const float* __restrict__ ln_g,
    const float* __restrict__ ln_b, const bf16_t* __restrict__ W,
    const float* __restrict__ pb, const float* __restrict__ ctab,
    const float* __restrict__ stab, bf16_t* __restrict__ qbf,
    bf16_t* __restrict__ kbf, bf16_t* __restrict__ vtb) {
    __shared__ bf16_t xns[32 * 264];   // 16.9 KB
    __shared__ bf16_t stg[8704];       // 17.0 KB (q/k: [32][264]; v: [256][34])
    int tid = threadIdx.x;
    int t0 = blockIdx.x * 32;
    int bu = t0 >> 9, a0 = t0 & 511;

    // ---- LN1 -> xns ----
#pragma unroll
    for (int it = 0; it < 2; ++it) {
        int row = it * 16 + (tid >> 4);
        int sub = tid & 15;
        const floatx4* zr = (const floatx4*)(z + (size_t)(t0 + row) * 256 + sub * 16);
        floatx4 v0 = zr[0], v1 = zr[1], v2 = zr[2], v3 = zr[3];
        float vals[16];
        ((floatx4*)vals)[0] = v0; ((floatx4*)vals)[1] = v1;
        ((floatx4*)vals)[2] = v2; ((floatx4*)vals)[3] = v3;
        float s = 0.f, q2 = 0.f;
#pragma unroll
        for (int i = 0; i < 16; ++i) { s += vals[i]; q2 += vals[i] * vals[i]; }
#pragma unroll
        for (int off = 8; off >= 1; off >>= 1) {
            s += __shfl_xor(s, off);
            q2 += __shfl_xor(q2, off);
        }
        float mu = s * (1.f / 256.f);
        float inv = rsqrtf(q2 * (1.f / 256.f) - mu * mu + 1e-5f);
        int cb = sub * 16;
        bf16x8 o0, o1;
#pragma unroll
        for (int i = 0; i < 8; ++i)
            o0[i] = (bf16_t)((vals[i] - mu) * inv * ln_g[cb + i] + ln_b[cb + i]);
#pragma unroll
        for (int i = 0; i < 8; ++i)
            o1[i] = (bf16_t)((vals[8 + i] - mu) * inv * ln_g[cb + 8 + i] + ln_b[cb + 8 + i]);
        *(bf16x8*)&xns[row * 264 + cb] = o0;
        *(bf16x8*)&xns[row * 264 + cb + 8] = o1;
    }
    __syncthreads();

    int wv = tid >> 6, lane = tid & 63, quad = lane >> 4, lidx = lane & 15;

    // ---- q/k sections (sec 0 = q, 1 = k): W rows as A-operand ----
#pragma unroll 1
    for (int sec = 0; sec < 2; ++sec) {
        bf16_t* __restrict__ dst = (sec == 0) ? qbf : kbf;
        floatx4 acc[4][2];
#pragma unroll
        for (int ntl = 0; ntl < 4; ++ntl) {
            int cb = wv * 64 + ntl * 16;           // within-sec column base
            int ht = cb >> 5;
            floatx4 b4 = *(const floatx4*)&pb[ht * 96 + sec * 32 + (cb & 31) + quad * 4];
            acc[ntl][0] = b4; acc[ntl][1] = b4;
        }
#pragma unroll 2
        for (int kc = 0; kc < 8; ++kc) {
            bf16x8 x0 = *(const bf16x8*)&xns[lidx * 264 + kc * 32 + quad * 8];
            bf16x8 x1 = *(const bf16x8*)&xns[(16 + lidx) * 264 + kc * 32 + quad * 8];
#pragma unroll
            for (int ntl = 0; ntl < 4; ++ntl) {
                int cb = wv * 64 + ntl * 16;
                int ht = cb >> 5;
                int n = ht * 96 + sec * 32 + (cb & 31) + lidx;
                bf16x8 wf = *(const bf16x8*)&W[(size_t)n * 256 + kc * 32 + quad * 8];
                acc[ntl][0] = MFMA16(wf, x0, acc[ntl][0]);
                acc[ntl][1] = MFMA16(wf, x1, acc[ntl][1]);
            }
        }
        // RoPE in-lane (acc regs r=0..3 are consecutive d), stage to LDS
        float scl = (sec == 0) ? 0.17677669529663687f : 1.0f;
#pragma unroll
        for (int ntl = 0; ntl < 4; ++ntl) {
            int cb = wv * 64 + ntl * 16;
            int d0 = (cb & 31) + quad * 4;         // multiple of 4
            int fi = d0 >> 1;                      // even, <= 14
#pragma unroll
            for (int tt = 0; tt < 2; ++tt) {
                int al = tt * 16 + lidx;
                int a = a0 + al;
                float cs0 = ctab[a * 16 + fi],     cs1 = ctab[a * 16 + fi + 1];
                float sn0 = stab[a * 16 + fi],     sn1 = stab[a * 16 + fi + 1];
                floatx4 v = acc[ntl][tt];
                bf16x4 o;
                o[0] = (bf16_t)((v[0] * cs0 - v[1] * sn0) * scl);
                o[1] = (bf16_t)((v[1] * cs0 + v[0] * sn0) * scl);
                o[2] = (bf16_t)((v[2] * cs1 - v[3] * sn1) * scl);
                o[3] = (bf16_t)((v[3] * cs1 + v[2] * sn1) * scl);
                *(bf16x4*)&stg[al * 264 + cb + quad * 4] = o;
            }
        }
        __syncthreads();
        // coalesced flush: 1024 x 16B chunks; wave writes 1KB contiguous
#pragma unroll
        for (int i = 0; i < 4; ++i) {
            int cid = i * 256 + tid;
            int chunk = cid & 3, al = (cid >> 2) & 31, ht = cid >> 7;
            bf16x8 vv = *(const bf16x8*)&stg[al * 264 + ht * 32 + chunk * 8];
            *(bf16x8*)&dst[((size_t)((bu * 8 + ht) * 512 + a0 + al)) * 32 + chunk * 8] = vv;
        }
        __syncthreads();
    }

    // ---- v section: X as A-operand; stage transposed [vcol][a_loc] ----
    {
        floatx4 acc[4][2];
#pragma unroll
        for (int ntl = 0; ntl < 4; ++ntl) {
            int cb = wv * 64 + ntl * 16;
            int ht = cb >> 5;
            float b = pb[ht * 96 + 64 + (cb & 31) + lidx];
            acc[ntl][0] = (floatx4){b, b, b, b};
            acc[ntl][1] = (floatx4){b, b, b, b};
        }
#pragma unroll 2
        for (int kc = 0; kc < 8; ++kc) {
            bf16x8 x0 = *(const bf16x8*)&xns[lidx * 264 + kc * 32 + quad * 8];
            bf16x8 x1 = *(const bf16x8*)&xns[(16 + lidx) * 264 + kc * 32 + quad * 8];
#pragma unroll
            for (int ntl = 0; ntl < 4; ++ntl) {
                int cb = wv * 64 + ntl * 16;
                int ht = cb >> 5;
                int n = ht * 96 + 64 + (cb & 31) + lidx;
                bf16x8 wf = *(const bf16x8*)&W[(size_t)n * 256 + kc * 32 + quad * 8];
                acc[ntl][0] = MFMA16(x0, wf, acc[ntl][0]);
                acc[ntl][1] = MFMA16(x1, wf, acc[ntl][1]);
            }
        }
#pragma unroll
        for (int ntl = 0; ntl < 4; ++ntl) {
            int vcol = wv * 64 + ntl * 16 + lidx;
#pragma unroll
            for (int tt = 0; tt < 2; ++tt)
#pragma unroll
                for (int r = 0; r < 4; ++r)
                    stg[vcol * 34 + tt * 16 + quad * 4 + r] = (bf16_t)acc[ntl][tt][r];
        }
        __syncthreads();
#pragma unroll
        for (int i = 0; i < 4; ++i) {
            int cid = i * 256 + tid;
            int chunk = cid & 3, vcol = cid >> 2;
            bf16x8 vv = *(const bf16x8*)&stg[vcol * 34 + chunk * 8];
            *(bf16x8*)&vtb[((size_t)(bu * 256 + vcol)) * 512 + a0 + chunk * 8] = vv;
        }
    }
}

// ---------------------------------------------------------------------------
// Attention: one block (512 thr = 8 waves) per (bu,h). Swapped QK^T
// (mfma(K,Q)) + permuted K-row feed so each lane's 16 exp'd scores ARE the
// PV A-fragment in-lane: zero P LDS traffic, zero cross-lane P exchange.
// Row-sums accumulate in-lane (query = lidx); 2-shuffle reduce + 4 shfl
// redistribution per q-tile. exp(s-8) via MFMA C-init (shift-invariant).
// All arrays loop-local & statically indexed (no scratch). LDS 64 KB.
// ---------------------------------------------------------------------------
__global__ __launch_bounds__(512, 4) void attn_kernel(
    const bf16_t* __restrict__ qbf, const bf16_t* __restrict__ kbf,
    const bf16_t* __restrict__ vtb, bf16_t* __restrict__ ob) {
    __shared__ bf16_t Kls[512 * 32];      // 32 KB
    __shared__ bf16_t Vt[32 * 512];       // 32 KB
    int tid = threadIdx.x;
    int wv = tid >> 6, lane = tid & 63, quad = lane >> 4, lidx = lane & 15;
    int bh = blockIdx.x;
    int bu = bh >> 3, h = bh & 7;
    size_t hb = (size_t)bh * (A_LEN * HD);

    // ---- stage K (row-swizzled) and V^T (pre-transposed in global) ----
#pragma unroll
    for (int i = 0; i < 4; ++i) {
        int c = tid + i * 512;            // 16B chunk id, 0..2047
        int key = c >> 2, blk = c & 3;
        bf16x8 kv = *(const bf16x8*)&kbf[hb + (size_t)c * 8];
        *(bf16x8*)&Kls[key * 32 + ((blk ^ (key & 3)) << 3)] = kv;
        int vrow = c >> 6, vblk = c & 63;
        bf16x8 vv = *(const bf16x8*)&vtb[hb + (size_t)c * 8];
        *(bf16x8*)&Vt[vrow * 512 + ((vblk ^ (vrow & 7)) << 3)] = vv;
    }
    __syncthreads();

    const floatx4 cm8 = (floatx4){-8.f, -8.f, -8.f, -8.f};
    const floatx4 zero4 = (floatx4){0.f, 0.f, 0.f, 0.f};
    // permuted K-row base within a 64-key block (t adds (t&1)*4 + (t>>1)*32)
    int krow = ((lidx >> 2) << 3) + (lidx & 3);
    int kswz = (quad ^ (lidx & 3)) << 3;

#pragma unroll 1
    for (int mt = 0; mt < 4; ++mt) {
        int q0 = wv * 64 + mt * 16;
        // Q fragment: content valid as B-operand (same lane layout as A)
        bf16x8 qfrag = *(const bf16x8*)&qbf[hb + (size_t)(q0 + lidx) * 32 + quad * 8];
        float l_ = 0.f;
        floatx4 Oacc[2];
        Oacc[0] = zero4; Oacc[1] = zero4;

#pragma unroll 1
        for (int kc = 0; kc < 8; ++kc) {
            // QK^T swapped: D[key][query]; lane holds query=lidx,
            // keys = quad*8 + (t&1)*4 + j + (t>>1)*32 (via permuted row feed)
            floatx4 sc[4];
#pragma unroll
            for (int t = 0; t < 4; ++t) {
                int row = kc * 64 + (t >> 1) * 32 + ((t & 1) << 2) + krow;
                bf16x8 kf = *(const bf16x8*)&Kls[row * 32 + kswz];
                sc[t] = MFMA16(kf, qfrag, cm8);   // s - 8 folded into C
            }
            float p[4][4];
#pragma unroll
            for (int t = 0; t < 4; ++t)
#pragma unroll
                for (int r = 0; r < 4; ++r) p[t][r] = __expf(sc[t][r]);
            // in-lane row-sum partial (query = lidx)
#pragma unroll
            for (int t = 0; t < 4; ++t)
                l_ += (p[t][0] + p[t][1]) + (p[t][2] + p[t][3]);
            // pack P directly as PV A-fragments (all in-lane)
            bf16x8 pa0, pa1;
#pragma unroll
            for (int r = 0; r < 4; ++r) {
                pa0[r]     = (bf16_t)p[0][r];
                pa0[4 + r] = (bf16_t)p[1][r];
                pa1[r]     = (bf16_t)p[2][r];
                pa1[4 + r] = (bf16_t)p[3][r];
            }
            // PV
#pragma unroll
            for (int nt = 0; nt < 2; ++nt) {
                int vr = nt * 16 + lidx;
                bf16x8 vf0 = *(const bf16x8*)&Vt[vr * 512 +
                    ((kc * 8 + ((0 * 4 + quad) ^ (lidx & 7))) << 3)];
                Oacc[nt] = MFMA16(pa0, vf0, Oacc[nt]);
                bf16x8 vf1 = *(const bf16x8*)&Vt[vr * 512 +
                    ((kc * 8 + ((1 * 4 + quad) ^ (lidx & 7))) << 3)];
                Oacc[nt] = MFMA16(pa1, vf1, Oacc[nt]);
            }
        }

        // ---- epilogue: reduce L across quads, redistribute, store ----
        float s = l_;
        s += __shfl_xor(s, 16);
        s += __shfl_xor(s, 32);           // all lanes: L[query=lidx]
#pragma unroll
        for (int r = 0; r < 4; ++r) {
            float inv = __builtin_amdgcn_rcpf(__shfl(s, quad * 4 + r));
            int tok = bu * 512 + q0 + quad * 4 + r;
#pragma unroll
            for (int nt = 0; nt < 2; ++nt)
                ob[(size_t)tok * 256 + h * 32 + nt * 16 + lidx] =
                    (bf16_t)(Oacc[nt][r] * inv);
        }
    }
}

// ---------------------------------------------------------------------------
// Fused tail: out = r1 + FFN(LN2(r1)),  r1 = z + attn@Wo^T + ff_b.
// 32 tokens/block, 256 thr (round-5 structure: r1 in regs, 65 us) + explicit
// depth-2 weight-fragment software pipeline (wfA/wfB ping-pong, fully
// unrolled kc -> static indexing, no scratch). Next-kc weight loads issued
// before current-kc MFMAs -> L2 latency hidden in-wave (the stall rounds
// 6/7 proved occupancy can't hide). First Wo preload overlaps A-staging.
// LDS 35.3 KB -> 4 blocks/CU. VGPR target ~112 < 128 cap of (256,4).
// ---------------------------------------------------------------------------
__global__ __launch_bounds__(256, 4) void tail_kernel(
    const bf16_t* __restrict__ X, const bf16_t* __restrict__ Wo,
    const float* __restrict__ obias, const float* __restrict__ zin,
    const float* __restrict__ ln_g, const float* __restrict__ ln_b,
    const bf16_t* __restrict__ W1, const float* __restrict__ b1,
    const bf16_t* __restrict__ W2, const float* __restrict__ b2,
    float* __restrict__ outp) {
    __shared__ float fbuf[32 * 264];   // 33.8 KB; bf16 view aliases phases
    __shared__ float red[32 * 8];
    __shared__ float mi[32 * 2];
    bf16_t* xbuf = (bf16_t*)fbuf;
    int tid = threadIdx.x;
    int t0 = blockIdx.x * 32;
    int wv = tid >> 6, lane = tid & 63, quad = lane >> 4, lidx = lane & 15;
    size_t wrow = (size_t)(wv * 64 + lidx) * 256 + quad * 8;  // +nt*16*256 +kc*32

    bf16x8 wfA[4], wfB[4];
    // Wo kc=0 preload overlaps the A-tile staging (independent of LDS)
#pragma unroll
    for (int nt = 0; nt < 4; ++nt)
        wfA[nt] = *(const bf16x8*)&Wo[wrow + (size_t)nt * 4096];

    // ---- stage A (attn out tile) into LDS, coalesced ----
    {
        int row = tid >> 3;               // 0..31
        int c0 = (tid & 7) * 32;          // 0..224
        const bf16x8* src = (const bf16x8*)&X[(size_t)(t0 + row) * 256 + c0];
        bf16x8* dst = (bf16x8*)&xbuf[row * 264 + c0];
        dst[0] = src[0]; dst[1] = src[1]; dst[2] = src[2]; dst[3] = src[3];
    }
    __syncthreads();

// depth-2 pipelined 32x256x256 GEMM: A from xbuf, B rows from WP.
#define GEMM_PIPE(WP, ACC)                                                   \
    do {                                                                     \
        _Pragma("unroll")                                                    \
        for (int kp = 0; kp < 4; ++kp) {                                     \
            _Pragma("unroll")                                                \
            for (int nt = 0; nt < 4; ++nt)                                   \
                wfB[nt] = *(const bf16x8*)&WP[wrow + (size_t)nt * 4096 +     \
                                              kp * 64 + 32];                 \
            bf16x8 a0 = *(const bf16x8*)&xbuf[lidx * 264 + kp * 64 + quad * 8]; \
            bf16x8 a1 = *(const bf16x8*)&xbuf[(16 + lidx) * 264 + kp * 64 + quad * 8]; \
            _Pragma("unroll")                                                \
            for (int nt = 0; nt < 4; ++nt) {                                 \
                ACC[nt][0] = MFMA16(a0, wfA[nt], ACC[nt][0]);                \
                ACC[nt][1] = MFMA16(a1, wfA[nt], ACC[nt][1]);                \
            }                                                                \
            if (kp < 3) {                                                    \
                _Pragma("unroll")                                            \
                for (int nt = 0; nt < 4; ++nt)                               \
                    wfA[nt] = *(const bf16x8*)&WP[wrow + (size_t)nt * 4096 + \
                                                  kp * 64 + 64];             \
            }                                                                \
            a0 = *(const bf16x8*)&xbuf[lidx * 264 + kp * 64 + 32 + quad * 8]; \
            a1 = *(const bf16x8*)&xbuf[(16 + lidx) * 264 + kp * 64 + 32 + quad * 8]; \
            _Pragma("unroll")                                                \
            for (int nt = 0; nt < 4; ++nt) {                                 \
                ACC[nt][0] = MFMA16(a0, wfB[nt], ACC[nt][0]);                \
                ACC[nt][1] = MFMA16(a1, wfB[nt], ACC[nt][1]);                \
            }                                                                \
        }                                                                    \
    } while (0)

    float r1[4][2][4];   // [nt][mt][r]
    {
        floatx4 acc[4][2];
#pragma unroll
        for (int i = 0; i < 4; ++i) {
            acc[i][0] = (floatx4){0.f, 0.f, 0.f, 0.f};
            acc[i][1] = (floatx4){0.f, 0.f, 0.f, 0.f};
        }
        GEMM_PIPE(Wo, acc);
#pragma unroll
        for (int nt = 0; nt < 4; ++nt) {
            int n = wv * 64 + nt * 16 + lidx;
            float b = obias[n];
#pragma unroll
            for (int mt = 0; mt < 2; ++mt)
#pragma unroll
                for (int r = 0; r < 4; ++r) {
                    size_t o = (size_t)(t0 + mt * 16 + quad * 4 + r) * 256 + n;
                    r1[nt][mt][r] = zin[o] + acc[nt][mt][r] + b;
                }
        }
    }

    // ---- LN2 statistics ----
#pragma unroll
    for (int mt = 0; mt < 2; ++mt)
#pragma unroll
        for (int r = 0; r < 4; ++r) {
            float s = 0.f, ss = 0.f;
#pragma unroll
            for (int nt = 0; nt < 4; ++nt) {
                float v = r1[nt][mt][r];
                s += v; ss += v * v;
            }
#pragma unroll
            for (int off = 8; off >= 1; off >>= 1) {
                s += __shfl_xor(s, off);
                ss += __shfl_xor(ss, off);
            }
            if (lidx == 0) {
                int row = mt * 16 + quad * 4 + r;
                red[row * 8 + wv * 2] = s;
                red[row * 8 + wv * 2 + 1] = ss;
            }
        }
    __syncthreads();
    if (tid < 32) {
        float s = 0.f, ss = 0.f;
#pragma unroll
        for (int w = 0; w < 4; ++w) {
            s += red[tid * 8 + w * 2];
            ss += red[tid * 8 + w * 2 + 1];
        }
        float mu = s * (1.f / 256.f);
        mi[tid * 2] = mu;
        mi[tid * 2 + 1] = rsqrtf(ss * (1.f / 256.f) - mu * mu + 1e-5f);
    }
    __syncthreads();

    // ---- LN2 apply -> xbuf (A-tile dead); W1 kc=0 preload overlaps ----
    {
#pragma unroll
        for (int nt = 0; nt < 4; ++nt)
            wfA[nt] = *(const bf16x8*)&W1[wrow + (size_t)nt * 4096];
        float gv[4], bv[4];
#pragma unroll
        for (int nt = 0; nt < 4; ++nt) {
            int n = wv * 64 + nt * 16 + lidx;
            gv[nt] = ln_g[n]; bv[nt] = ln_b[n];
        }
#pragma unroll
        for (int mt = 0; mt < 2; ++mt)
#pragma unroll
            for (int r = 0; r < 4; ++r) {
                int row = mt * 16 + quad * 4 + r;
                float mu = mi[row * 2], inv = mi[row * 2 + 1];
#pragma unroll
                for (int nt = 0; nt < 4; ++nt) {
                    int n = wv * 64 + nt * 16 + lidx;
                    xbuf[row * 264 + n] =
                        (bf16_t)((r1[nt][mt][r] - mu) * inv * gv[nt] + bv[nt]);
                }
            }
    }
    __syncthreads();

    // ---- W1 GEMM + GELU, result back into xbuf ----
    {
        floatx4 acc[4][2];
#pragma unroll
        for (int i = 0; i < 4; ++i) {
            acc[i][0] = (floatx4){0.f, 0.f, 0.f, 0.f};
            acc[i][1] = (floatx4){0.f, 0.f, 0.f, 0.f};
        }
        GEMM_PIPE(W1, acc);
        __syncthreads();   // all reads of LN-out done before overwrite
        // W2 kc=0 preload overlaps GELU epilogue
#pragma unroll
        for (int nt = 0; nt < 4; ++nt)
            wfB[nt] = *(const bf16x8*)&W2[wrow + (size_t)nt * 4096];
#pragma unroll
        for (int nt = 0; nt < 4; ++nt) {
            int n = wv * 64 + nt * 16 + lidx;
            float b = b1[n];
#pragma unroll
            for (int mt = 0; mt < 2; ++mt)
#pragma unroll
                for (int r = 0; r < 4; ++r) {
                    float x = acc[nt][mt][r] + b;
                    xbuf[(mt * 16 + quad * 4 + r) * 264 + n] = (bf16_t)gelu_f(x);
                }
        }
#pragma unroll
        for (int nt = 0; nt < 4; ++nt) wfA[nt] = wfB[nt];
    }
    __syncthreads();

    // ---- W2 GEMM, final residual into fbuf (f32) ----
    {
        floatx4 acc[4][2];
#pragma unroll
        for (int i = 0; i < 4; ++i) {
            acc[i][0] = (floatx4){0.f, 0.f, 0.f, 0.f};
            acc[i][1] = (floatx4){0.f, 0.f, 0.f, 0.f};
        }
        GEMM_PIPE(W2, acc);
        __syncthreads();   // all reads of GELU-out done before f32 overwrite
#pragma unroll
        for (int nt = 0; nt < 4; ++nt) {
            int n = wv * 64 + nt * 16 + lidx;
            float b = b2[n];
#pragma unroll
            for (int mt = 0; mt < 2; ++mt)
#pragma unroll
                for (int r = 0; r < 4; ++r)
                    fbuf[(mt * 16 + quad * 4 + r) * 264 + n] =
                        r1[nt][mt][r] + acc[nt][mt][r] + b;
        }
    }
    __syncthreads();

    // ---- coalesced flush: full 1 KB rows, float4 per lane ----
#pragma unroll
    for (int i = 0; i < 8; ++i) {
        int fid = i * 256 + tid;
        int row = fid >> 6;
        int c4 = (fid & 63) * 4;
        *(floatx4*)&outp[(size_t)(t0 + row) * 256 + c4] =
            *(const floatx4*)&fbuf[row * 264 + c4];
    }
#undef GEMM_PIPE
}

// ---------------------------------------------------------------------------
extern "C" void kernel_launch(void* const* d_in, const int* in_sizes, int n_in,
                              void* d_out, int out_size, void* d_ws, size_t ws_size,
                              hipStream_t stream) {
    const float* z      = (const float*)d_in[0];
    const float* ln1_g  = (const float*)d_in[1];
    const float* ln1_b  = (const float*)d_in[2];
    const float* proj_v = (const float*)d_in[3];
    const float* proj_g = (const float*)d_in[4];
    const float* proj_b = (const float*)d_in[5];
    const float* ff_v   = (const float*)d_in[6];
    const float* ff_g   = (const float*)d_in[7];
    const float* ff_b   = (const float*)d_in[8];
    const float* ln2_g  = (const float*)d_in[9];
    const float* ln2_b  = (const float*)d_in[10];
    const float* w1_v   = (const float*)d_in[11];
    const float* w1_g   = (const float*)d_in[12];
    const float* w1_b   = (const float*)d_in[13];
    const float* w2_v   = (const float*)d_in[14];
    const float* w2_g   = (const float*)d_in[15];
    const float* w2_b   = (const float*)d_in[16];
    float* out = (float*)d_out;

    char* p = (char*)d_ws;
    bf16_t* Wall = (bf16_t*)p; p += (size_t)1536 * 256 * 2;
    float* ctab  = (float*)p;  p += 8192 * 4;
    float* stab  = (float*)p;  p += 8192 * 4;
    // q/k: [bh][a][d]; vtb: [bh][d][a]; each 512*512*32 = TOK*256 elems
    bf16_t* qbf  = (bf16_t*)p; p += (size_t)TOK * 256 * 2;
    bf16_t* kbf  = (bf16_t*)p; p += (size_t)TOK * 256 * 2;
    bf16_t* vtb  = (bf16_t*)p; p += (size_t)TOK * 256 * 2;
    bf16_t* abuf = (bf16_t*)p; p += (size_t)TOK * 256 * 2;

    const bf16_t* Wqkv = Wall;
    const bf16_t* Wo   = Wall + (size_t)768 * 256;
    const bf16_t* W1   = Wall + (size_t)1024 * 256;
    const bf16_t* W2   = Wall + (size_t)1280 * 256;

    setup_kernel<<<1664, 64, 0, stream>>>(proj_v, proj_g, ff_v, ff_g,
                                          w1_v, w1_g, w2_v, w2_g,
                                          Wall, ctab, stab);
    qkv_kernel<<<TOK / 32, 256, 0, stream>>>(z, ln1_g, ln1_b, Wqkv, proj_b,
                                             ctab, stab, qbf, kbf, vtb);
    attn_kernel<<<64 * 8, 512, 0, stream>>>(qbf, kbf, vtb, abuf);
    tail_kernel<<<TOK / 32, 256, 0, stream>>>(abuf, Wo, ff_b, z, ln2_g, ln2_b,
                                              W1, w1_b, W2, w2_b, out);
}

// Round 10
// 243.099 us; speedup vs baseline: 1.0615x; 1.0080x over previous
//
#include <hip/hip_runtime.h>
#include <cmath>

#define EMB 256
#define NHEAD 8
#define HD 32
#define A_LEN 512
#define TOK 32768

typedef __bf16 bf16_t;
typedef __bf16 bf16x8 __attribute__((ext_vector_type(8)));
typedef __bf16 bf16x4 __attribute__((ext_vector_type(4)));
typedef float floatx4 __attribute__((ext_vector_type(4)));

#define MFMA16(a, b, c) __builtin_amdgcn_mfma_f32_16x16x32_bf16((a), (b), (c), 0, 0, 0)

// Fast exact-gelu: erf via Abramowitz-Stegun 7.1.26 (|err|<1.5e-7, far below
// bf16 storage rounding). ~12 VALU + 1 exp vs ~30 for libm erff.
__device__ __forceinline__ float gelu_f(float x) {
    float ax = fabsf(x) * 0.7071067811865476f;
    float t = __builtin_amdgcn_rcpf(fmaf(0.3275911f, ax, 1.0f));
    float poly = t * fmaf(t, fmaf(t, fmaf(t, fmaf(t, 1.061405429f, -1.453152027f),
                          1.421413741f), -0.284496736f), 0.254829592f);
    float erfv = 1.0f - poly * __expf(-ax * ax);
    erfv = copysignf(erfv, x);
    return 0.5f * x * (1.0f + erfv);
}

// ---------------------------------------------------------------------------
// Setup: weight_norm all 4 weights -> bf16 rows in Wall, plus RoPE cos/sin
// tables. Blocks 0..1535: one wave per weight row. Blocks 1536..1663: table.
// ---------------------------------------------------------------------------
__global__ __launch_bounds__(64) void setup_kernel(
    const float* __restrict__ proj_v, const float* __restrict__ proj_g,
    const float* __restrict__ ff_v, const float* __restrict__ ff_g,
    const float* __restrict__ w1_v, const float* __restrict__ w1_g,
    const float* __restrict__ w2_v, const float* __restrict__ w2_g,
    bf16_t* __restrict__ Wall, float* __restrict__ ctab,
    float* __restrict__ stab) {
    int b = blockIdx.x;
    int lane = threadIdx.x;
    if (b < 1536) {
        const float* v; const float* g; int r;
        if (b < 768)       { v = proj_v; g = proj_g; r = b; }
        else if (b < 1024) { v = ff_v;   g = ff_g;   r = b - 768; }
        else if (b < 1280) { v = w1_v;   g = w1_g;   r = b - 1024; }
        else               { v = w2_v;   g = w2_g;   r = b - 1280; }
        const floatx4* vr = (const floatx4*)(v + (size_t)r * 256);
        floatx4 x = vr[lane];
        float ss = x[0] * x[0] + x[1] * x[1] + x[2] * x[2] + x[3] * x[3];
#pragma unroll
        for (int off = 32; off >= 1; off >>= 1) ss += __shfl_xor(ss, off);
        float sc = g[r] * rsqrtf(ss);
        bf16x4 o;
        o[0] = (bf16_t)(x[0] * sc); o[1] = (bf16_t)(x[1] * sc);
        o[2] = (bf16_t)(x[2] * sc); o[3] = (bf16_t)(x[3] * sc);
        ((bf16x4*)(Wall + (size_t)b * 256))[lane] = o;
    } else {
        int idx = (b - 1536) * 64 + lane;     // 0..8191 = a*16 + i
        int a = idx >> 4, i = idx & 15;
        float freq = expf(-(float)(2 * i) * 0.2878231366242558f); // ln(1e4)/32
        float ang = (float)a * freq;
        ctab[idx] = cosf(ang);
        stab[idx] = sinf(ang);
    }
}

// ---------------------------------------------------------------------------
// QKV: 32 tokens/block (1024 blocks -> 3 blocks/CU at (256,3)). LN1 -> bf16
// xns (LDS). q/k sections: W as MFMA *A*-operand so each lane's 4 acc regs
// are 4 CONSECUTIVE output dims of one token -> RoPE pairs in-lane. Bias in
// MFMA C-init. kc loops FULLY unrolled + relaxed VGPR cap (168) so the
// compiler hoists weight loads across iterations (compiler-scheduled
// pipelining; rounds 6/7 showed occupancy isn't the binding constraint,
// in-flight loads are). Results staged in LDS, coalesced flush.
// v: transposed staging -> [bh][d][a]. LDS 33.9 KB.
// ---------------------------------------------------------------------------
__global__ __launch_bounds__(256, 3) void qkv_kernel(
    const float* __restrict__ z, const float* __restrict__ ln_g,
    const float* __restrict__ ln_b, const bf16_t* __restrict__ W,
    const float* __restrict__ pb, const float* __restrict__ ctab,
    const float* __restrict__ stab, bf16_t* __restrict__ qbf,
    bf16_t* __restrict__ kbf, bf16_t* __restrict__ vtb) {
    __shared__ bf16_t xns[32 * 264];   // 16.9 KB
    __shared__ bf16_t stg[8704];       // 17.0 KB (q/k: [32][264]; v: [256][34])
    int tid = threadIdx.x;
    int t0 = blockIdx.x * 32;
    int bu = t0 >> 9, a0 = t0 & 511;

    // ---- LN1 -> xns ----
#pragma unroll
    for (int it = 0; it < 2; ++it) {
        int row = it * 16 + (tid >> 4);
        int sub = tid & 15;
        const floatx4* zr = (const floatx4*)(z + (size_t)(t0 + row) * 256 + sub * 16);
        floatx4 v0 = zr[0], v1 = zr[1], v2 = zr[2], v3 = zr[3];
        float vals[16];
        ((floatx4*)vals)[0] = v0; ((floatx4*)vals)[1] = v1;
        ((floatx4*)vals)[2] = v2; ((floatx4*)vals)[3] = v3;
        float s = 0.f, q2 = 0.f;
#pragma unroll
        for (int i = 0; i < 16; ++i) { s += vals[i]; q2 += vals[i] * vals[i]; }
#pragma unroll
        for (int off = 8; off >= 1; off >>= 1) {
            s += __shfl_xor(s, off);
            q2 += __shfl_xor(q2, off);
        }
        float mu = s * (1.f / 256.f);
        float inv = rsqrtf(q2 * (1.f / 256.f) - mu * mu + 1e-5f);
        int cb = sub * 16;
        bf16x8 o0, o1;
#pragma unroll
        for (int i = 0; i < 8; ++i)
            o0[i] = (bf16_t)((vals[i] - mu) * inv * ln_g[cb + i] + ln_b[cb + i]);
#pragma unroll
        for (int i = 0; i < 8; ++i)
            o1[i] = (bf16_t)((vals[8 + i] - mu) * inv * ln_g[cb + 8 + i] + ln_b[cb + 8 + i]);
        *(bf16x8*)&xns[row * 264 + cb] = o0;
        *(bf16x8*)&xns[row * 264 + cb + 8] = o1;
    }
    __syncthreads();

    int wv = tid >> 6, lane = tid & 63, quad = lane >> 4, lidx = lane & 15;

    // ---- q/k sections (sec 0 = q, 1 = k): W rows as A-operand ----
#pragma unroll 1
    for (int sec = 0; sec < 2; ++sec) {
        bf16_t* __restrict__ dst = (sec == 0) ? qbf : kbf;
        floatx4 acc[4][2];
#pragma unroll
        for (int ntl = 0; ntl < 4; ++ntl) {
            int cb = wv * 64 + ntl * 16;           // within-sec column base
            int ht = cb >> 5;
            floatx4 b4 = *(const floatx4*)&pb[ht * 96 + sec * 32 + (cb & 31) + quad * 4];
            acc[ntl][0] = b4; acc[ntl][1] = b4;
        }
#pragma unroll
        for (int kc = 0; kc < 8; ++kc) {
            bf16x8 x0 = *(const bf16x8*)&xns[lidx * 264 + kc * 32 + quad * 8];
            bf16x8 x1 = *(const bf16x8*)&xns[(16 + lidx) * 264 + kc * 32 + quad * 8];
#pragma unroll
            for (int ntl = 0; ntl < 4; ++ntl) {
                int cb = wv * 64 + ntl * 16;
                int ht = cb >> 5;
                int n = ht * 96 + sec * 32 + (cb & 31) + lidx;
                bf16x8 wf = *(const bf16x8*)&W[(size_t)n * 256 + kc * 32 + quad * 8];
                acc[ntl][0] = MFMA16(wf, x0, acc[ntl][0]);
                acc[ntl][1] = MFMA16(wf, x1, acc[ntl][1]);
            }
        }
        // RoPE in-lane (acc regs r=0..3 are consecutive d), stage to LDS
        float scl = (sec == 0) ? 0.17677669529663687f : 1.0f;
#pragma unroll
        for (int ntl = 0; ntl < 4; ++ntl) {
            int cb = wv * 64 + ntl * 16;
            int d0 = (cb & 31) + quad * 4;         // multiple of 4
            int fi = d0 >> 1;                      // even, <= 14
#pragma unroll
            for (int tt = 0; tt < 2; ++tt) {
                int al = tt * 16 + lidx;
                int a = a0 + al;
                float cs0 = ctab[a * 16 + fi],     cs1 = ctab[a * 16 + fi + 1];
                float sn0 = stab[a * 16 + fi],     sn1 = stab[a * 16 + fi + 1];
                floatx4 v = acc[ntl][tt];
                bf16x4 o;
                o[0] = (bf16_t)((v[0] * cs0 - v[1] * sn0) * scl);
                o[1] = (bf16_t)((v[1] * cs0 + v[0] * sn0) * scl);
                o[2] = (bf16_t)((v[2] * cs1 - v[3] * sn1) * scl);
                o[3] = (bf16_t)((v[3] * cs1 + v[2] * sn1) * scl);
                *(bf16x4*)&stg[al * 264 + cb + quad * 4] = o;
            }
        }
        __syncthreads();
        // coalesced flush: 1024 x 16B chunks; wave writes 1KB contiguous
#pragma unroll
        for (int i = 0; i < 4; ++i) {
            int cid = i * 256 + tid;
            int chunk = cid & 3, al = (cid >> 2) & 31, ht = cid >> 7;
            bf16x8 vv = *(const bf16x8*)&stg[al * 264 + ht * 32 + chunk * 8];
            *(bf16x8*)&dst[((size_t)((bu * 8 + ht) * 512 + a0 + al)) * 32 + chunk * 8] = vv;
        }
        __syncthreads();
    }

    // ---- v section: X as A-operand; stage transposed [vcol][a_loc] ----
    {
        floatx4 acc[4][2];
#pragma unroll
        for (int ntl = 0; ntl < 4; ++ntl) {
            int cb = wv * 64 + ntl * 16;
            int ht = cb >> 5;
            float b = pb[ht * 96 + 64 + (cb & 31) + lidx];
            acc[ntl][0] = (floatx4){b, b, b, b};
            acc[ntl][1] = (floatx4){b, b, b, b};
        }
#pragma unroll
        for (int kc = 0; kc < 8; ++kc) {
            bf16x8 x0 = *(const bf16x8*)&xns[lidx * 264 + kc * 32 + quad * 8];
            bf16x8 x1 = *(const bf16x8*)&xns[(16 + lidx) * 264 + kc * 32 + quad * 8];
#pragma unroll
            for (int ntl = 0; ntl < 4; ++ntl) {
                int cb = wv * 64 + ntl * 16;
                int ht = cb >> 5;
                int n = ht * 96 + 64 + (cb & 31) + lidx;
                bf16x8 wf = *(const bf16x8*)&W[(size_t)n * 256 + kc * 32 + quad * 8];
                acc[ntl][0] = MFMA16(x0, wf, acc[ntl][0]);
                acc[ntl][1] = MFMA16(x1, wf, acc[ntl][1]);
            }
        }
#pragma unroll
        for (int ntl = 0; ntl < 4; ++ntl) {
            int vcol = wv * 64 + ntl * 16 + lidx;
#pragma unroll
            for (int tt = 0; tt < 2; ++tt)
#pragma unroll
                for (int r = 0; r < 4; ++r)
                    stg[vcol * 34 + tt * 16 + quad * 4 + r] = (bf16_t)acc[ntl][tt][r];
        }
        __syncthreads();
#pragma unroll
        for (int i = 0; i < 4; ++i) {
            int cid = i * 256 + tid;
            int chunk = cid & 3, vcol = cid >> 2;
            bf16x8 vv = *(const bf16x8*)&stg[vcol * 34 + chunk * 8];
            *(bf16x8*)&vtb[((size_t)(bu * 256 + vcol)) * 512 + a0 + chunk * 8] = vv;
        }
    }
}

// ---------------------------------------------------------------------------
// Attention: one block (512 thr = 8 waves) per (bu,h). Swapped QK^T
// (mfma(K,Q)) + permuted K-row feed so each lane's 16 exp'd scores ARE the
// PV A-fragment in-lane: zero P LDS traffic, zero cross-lane P exchange.
// Row-sums accumulate in-lane (query = lidx); 2-shuffle reduce + 4 shfl
// redistribution per q-tile. exp(s-8) via MFMA C-init (shift-invariant).
// All arrays loop-local & statically indexed (no scratch). LDS 64 KB.
// ---------------------------------------------------------------------------
__global__ __launch_bounds__(512, 4) void attn_kernel(
    const bf16_t* __restrict__ qbf, const bf16_t* __restrict__ kbf,
    const bf16_t* __restrict__ vtb, bf16_t* __restrict__ ob) {
    __shared__ bf16_t Kls[512 * 32];      // 32 KB
    __shared__ bf16_t Vt[32 * 512];       // 32 KB
    int tid = threadIdx.x;
    int wv = tid >> 6, lane = tid & 63, quad = lane >> 4, lidx = lane & 15;
    int bh = blockIdx.x;
    int bu = bh >> 3, h = bh & 7;
    size_t hb = (size_t)bh * (A_LEN * HD);

    // ---- stage K (row-swizzled) and V^T (pre-transposed in global) ----
#pragma unroll
    for (int i = 0; i < 4; ++i) {
        int c = tid + i * 512;            // 16B chunk id, 0..2047
        int key = c >> 2, blk = c & 3;
        bf16x8 kv = *(const bf16x8*)&kbf[hb + (size_t)c * 8];
        *(bf16x8*)&Kls[key * 32 + ((blk ^ (key & 3)) << 3)] = kv;
        int vrow = c >> 6, vblk = c & 63;
        bf16x8 vv = *(const bf16x8*)&vtb[hb + (size_t)c * 8];
        *(bf16x8*)&Vt[vrow * 512 + ((vblk ^ (vrow & 7)) << 3)] = vv;
    }
    __syncthreads();

    const floatx4 cm8 = (floatx4){-8.f, -8.f, -8.f, -8.f};
    const floatx4 zero4 = (floatx4){0.f, 0.f, 0.f, 0.f};
    // permuted K-row base within a 64-key block (t adds (t&1)*4 + (t>>1)*32)
    int krow = ((lidx >> 2) << 3) + (lidx & 3);
    int kswz = (quad ^ (lidx & 3)) << 3;

#pragma unroll 1
    for (int mt = 0; mt < 4; ++mt) {
        int q0 = wv * 64 + mt * 16;
        // Q fragment: content valid as B-operand (same lane layout as A)
        bf16x8 qfrag = *(const bf16x8*)&qbf[hb + (size_t)(q0 + lidx) * 32 + quad * 8];
        float l_ = 0.f;
        floatx4 Oacc[2];
        Oacc[0] = zero4; Oacc[1] = zero4;

#pragma unroll 1
        for (int kc = 0; kc < 8; ++kc) {
            // QK^T swapped: D[key][query]; lane holds query=lidx,
            // keys = quad*8 + (t&1)*4 + j + (t>>1)*32 (via permuted row feed)
            floatx4 sc[4];
#pragma unroll
            for (int t = 0; t < 4; ++t) {
                int row = kc * 64 + (t >> 1) * 32 + ((t & 1) << 2) + krow;
                bf16x8 kf = *(const bf16x8*)&Kls[row * 32 + kswz];
                sc[t] = MFMA16(kf, qfrag, cm8);   // s - 8 folded into C
            }
            float p[4][4];
#pragma unroll
            for (int t = 0; t < 4; ++t)
#pragma unroll
                for (int r = 0; r < 4; ++r) p[t][r] = __expf(sc[t][r]);
            // in-lane row-sum partial (query = lidx)
#pragma unroll
            for (int t = 0; t < 4; ++t)
                l_ += (p[t][0] + p[t][1]) + (p[t][2] + p[t][3]);
            // pack P directly as PV A-fragments (all in-lane)
            bf16x8 pa0, pa1;
#pragma unroll
            for (int r = 0; r < 4; ++r) {
                pa0[r]     = (bf16_t)p[0][r];
                pa0[4 + r] = (bf16_t)p[1][r];
                pa1[r]     = (bf16_t)p[2][r];
                pa1[4 + r] = (bf16_t)p[3][r];
            }
            // PV
#pragma unroll
            for (int nt = 0; nt < 2; ++nt) {
                int vr = nt * 16 + lidx;
                bf16x8 vf0 = *(const bf16x8*)&Vt[vr * 512 +
                    ((kc * 8 + ((0 * 4 + quad) ^ (lidx & 7))) << 3)];
                Oacc[nt] = MFMA16(pa0, vf0, Oacc[nt]);
                bf16x8 vf1 = *(const bf16x8*)&Vt[vr * 512 +
                    ((kc * 8 + ((1 * 4 + quad) ^ (lidx & 7))) << 3)];
                Oacc[nt] = MFMA16(pa1, vf1, Oacc[nt]);
            }
        }

        // ---- epilogue: reduce L across quads, redistribute, store ----
        float s = l_;
        s += __shfl_xor(s, 16);
        s += __shfl_xor(s, 32);           // all lanes: L[query=lidx]
#pragma unroll
        for (int r = 0; r < 4; ++r) {
            float inv = __builtin_amdgcn_rcpf(__shfl(s, quad * 4 + r));
            int tok = bu * 512 + q0 + quad * 4 + r;
#pragma unroll
            for (int nt = 0; nt < 2; ++nt)
                ob[(size_t)tok * 256 + h * 32 + nt * 16 + lidx] =
                    (bf16_t)(Oacc[nt][r] * inv);
        }
    }
}

// ---------------------------------------------------------------------------
// Fused tail: out = r1 + FFN(LN2(r1)),  r1 = z + attn@Wo^T + ff_b.
// 32 tokens/block, 256 thr, r1 in regs + depth-2 weight-fragment pipeline
// (wfA/wfB ping-pong, fully unrolled, static indexing). LDS 35.3 KB.
// ---------------------------------------------------------------------------
__global__ __launch_bounds__(256, 4) void tail_kernel(
    const bf16_t* __restrict__ X, const bf16_t* __restrict__ Wo,
    const float* __restrict__ obias, const float* __restrict__ zin,
    const float* __restrict__ ln_g, const float* __restrict__ ln_b,
    const bf16_t* __restrict__ W1, const float* __restrict__ b1,
    const bf16_t* __restrict__ W2, const float* __restrict__ b2,
    float* __restrict__ outp) {
    __shared__ float fbuf[32 * 264];   // 33.8 KB; bf16 view aliases phases
    __shared__ float red[32 * 8];
    __shared__ float mi[32 * 2];
    bf16_t* xbuf = (bf16_t*)fbuf;
    int tid = threadIdx.x;
    int t0 = blockIdx.x * 32;
    int wv = tid >> 6, lane = tid & 63, quad = lane >> 4, lidx = lane & 15;
    size_t wrow = (size_t)(wv * 64 + lidx) * 256 + quad * 8;  // +nt*16*256 +kc*32

    bf16x8 wfA[4], wfB[4];
    // Wo kc=0 preload overlaps the A-tile staging (independent of LDS)
#pragma unroll
    for (int nt = 0; nt < 4; ++nt)
        wfA[nt] = *(const bf16x8*)&Wo[wrow + (size_t)nt * 4096];

    // ---- stage A (attn out tile) into LDS, coalesced ----
    {
        int row = tid >> 3;               // 0..31
        int c0 = (tid & 7) * 32;          // 0..224
        const bf16x8* src = (const bf16x8*)&X[(size_t)(t0 + row) * 256 + c0];
        bf16x8* dst = (bf16x8*)&xbuf[row * 264 + c0];
        dst[0] = src[0]; dst[1] = src[1]; dst[2] = src[2]; dst[3] = src[3];
    }
    __syncthreads();

// depth-2 pipelined 32x256x256 GEMM: A from xbuf, B rows from WP.
#define GEMM_PIPE(WP, ACC)                                                   \
    do {                                                                     \
        _Pragma("unroll")                                                    \
        for (int kp = 0; kp < 4; ++kp) {                                     \
            _Pragma("unroll")                                                \
            for (int nt = 0; nt < 4; ++nt)                                   \
                wfB[nt] = *(const bf16x8*)&WP[wrow + (size_t)nt * 4096 +     \
                                              kp * 64 + 32];                 \
            bf16x8 a0 = *(const bf16x8*)&xbuf[lidx * 264 + kp * 64 + quad * 8]; \
            bf16x8 a1 = *(const bf16x8*)&xbuf[(16 + lidx) * 264 + kp * 64 + quad * 8]; \
            _Pragma("unroll")                                                \
            for (int nt = 0; nt < 4; ++nt) {                                 \
                ACC[nt][0] = MFMA16(a0, wfA[nt], ACC[nt][0]);                \
                ACC[nt][1] = MFMA16(a1, wfA[nt], ACC[nt][1]);                \
            }                                                                \
            if (kp < 3) {                                                    \
                _Pragma("unroll")                                            \
                for (int nt = 0; nt < 4; ++nt)                               \
                    wfA[nt] = *(const bf16x8*)&WP[wrow + (size_t)nt * 4096 + \
                                                  kp * 64 + 64];             \
            }                                                                \
            a0 = *(const bf16x8*)&xbuf[lidx * 264 + kp * 64 + 32 + quad * 8]; \
            a1 = *(const bf16x8*)&xbuf[(16 + lidx) * 264 + kp * 64 + 32 + quad * 8]; \
            _Pragma("unroll")                                                \
            for (int nt = 0; nt < 4; ++nt) {                                 \
                ACC[nt][0] = MFMA16(a0, wfB[nt], ACC[nt][0]);                \
                ACC[nt][1] = MFMA16(a1, wfB[nt], ACC[nt][1]);                \
            }                                                                \
        }                                                                    \
    } while (0)

    float r1[4][2][4];   // [nt][mt][r]
    {
        floatx4 acc[4][2];
#pragma unroll
        for (int i = 0; i < 4; ++i) {
            acc[i][0] = (floatx4){0.f, 0.f, 0.f, 0.f};
            acc[i][1] = (floatx4){0.f, 0.f, 0.f, 0.f};
        }
        GEMM_PIPE(Wo, acc);
#pragma unroll
        for (int nt = 0; nt < 4; ++nt) {
            int n = wv * 64 + nt * 16 + lidx;
            float b = obias[n];
#pragma unroll
            for (int mt = 0; mt < 2; ++mt)
#pragma unroll
                for (int r = 0; r < 4; ++r) {
                    size_t o = (size_t)(t0 + mt * 16 + quad * 4 + r) * 256 + n;
                    r1[nt][mt][r] = zin[o] + acc[nt][mt][r] + b;
                }
        }
    }

    // ---- LN2 statistics ----
#pragma unroll
    for (int mt = 0; mt < 2; ++mt)
#pragma unroll
        for (int r = 0; r < 4; ++r) {
            float s = 0.f, ss = 0.f;
#pragma unroll
            for (int nt = 0; nt < 4; ++nt) {
                float v = r1[nt][mt][r];
                s += v; ss += v * v;
            }
#pragma unroll
            for (int off = 8; off >= 1; off >>= 1) {
                s += __shfl_xor(s, off);
                ss += __shfl_xor(ss, off);
            }
            if (lidx == 0) {
                int row = mt * 16 + quad * 4 + r;
                red[row * 8 + wv * 2] = s;
                red[row * 8 + wv * 2 + 1] = ss;
            }
        }
    __syncthreads();
    if (tid < 32) {
        float s = 0.f, ss = 0.f;
#pragma unroll
        for (int w = 0; w < 4; ++w) {
            s += red[tid * 8 + w * 2];
            ss += red[tid * 8 + w * 2 + 1];
        }
        float mu = s * (1.f / 256.f);
        mi[tid * 2] = mu;
        mi[tid * 2 + 1] = rsqrtf(ss * (1.f / 256.f) - mu * mu + 1e-5f);
    }
    __syncthreads();

    // ---- LN2 apply -> xbuf (A-tile dead); W1 kc=0 preload overlaps ----
    {
#pragma unroll
        for (int nt = 0; nt < 4; ++nt)
            wfA[nt] = *(const bf16x8*)&W1[wrow + (size_t)nt * 4096];
        float gv[4], bv[4];
#pragma unroll
        for (int nt = 0; nt < 4; ++nt) {
            int n = wv * 64 + nt * 16 + lidx;
            gv[nt] = ln_g[n]; bv[nt] = ln_b[n];
        }
#pragma unroll
        for (int mt = 0; mt < 2; ++mt)
#pragma unroll
            for (int r = 0; r < 4; ++r) {
                int row = mt * 16 + quad * 4 + r;
                float mu = mi[row * 2], inv = mi[row * 2 + 1];
#pragma unroll
                for (int nt = 0; nt < 4; ++nt) {
                    int n = wv * 64 + nt * 16 + lidx;
                    xbuf[row * 264 + n] =
                        (bf16_t)((r1[nt][mt][r] - mu) * inv * gv[nt] + bv[nt]);
                }
            }
    }
    __syncthreads();

    // ---- W1 GEMM + GELU, result back into xbuf ----
    {
        floatx4 acc[4][2];
#pragma unroll
        for (int i = 0; i < 4; ++i) {
            acc[i][0] = (floatx4){0.f, 0.f, 0.f, 0.f};
            acc[i][1] = (floatx4){0.f, 0.f, 0.f, 0.f};
        }
        GEMM_PIPE(W1, acc);
        __syncthreads();   // all reads of LN-out done before overwrite
        // W2 kc=0 preload overlaps GELU epilogue
#pragma unroll
        for (int nt = 0; nt < 4; ++nt)
            wfB[nt] = *(const bf16x8*)&W2[wrow + (size_t)nt * 4096];
#pragma unroll
        for (int nt = 0; nt < 4; ++nt) {
            int n = wv * 64 + nt * 16 + lidx;
            float b = b1[n];
#pragma unroll
            for (int mt = 0; mt < 2; ++mt)
#pragma unroll
                for (int r = 0; r < 4; ++r) {
                    float x = acc[nt][mt][r] + b;
                    xbuf[(mt * 16 + quad * 4 + r) * 264 + n] = (bf16_t)gelu_f(x);
                }
        }
#pragma unroll
        for (int nt = 0; nt < 4; ++nt) wfA[nt] = wfB[nt];
    }
    __syncthreads();

    // ---- W2 GEMM, final residual into fbuf (f32) ----
    {
        floatx4 acc[4][2];
#pragma unroll
        for (int i = 0; i < 4; ++i) {
            acc[i][0] = (floatx4){0.f, 0.f, 0.f, 0.f};
            acc[i][1] = (floatx4){0.f, 0.f, 0.f, 0.f};
        }
        GEMM_PIPE(W2, acc);
        __syncthreads();   // all reads of GELU-out done before f32 overwrite
#pragma unroll
        for (int nt = 0; nt < 4; ++nt) {
            int n = wv * 64 + nt * 16 + lidx;
            float b = b2[n];
#pragma unroll
            for (int mt = 0; mt < 2; ++mt)
#pragma unroll
                for (int r = 0; r < 4; ++r)
                    fbuf[(mt * 16 + quad * 4 + r) * 264 + n] =
                        r1[nt][mt][r] + acc[nt][mt][r] + b;
        }
    }
    __syncthreads();

    // ---- coalesced flush: full 1 KB rows, float4 per lane ----
#pragma unroll
    for (int i = 0; i < 8; ++i) {
        int fid = i * 256 + tid;
        int row = fid >> 6;
        int c4 = (fid & 63) * 4;
        *(floatx4*)&outp[(size_t)(t0 + row) * 256 + c4] =
            *(const floatx4*)&fbuf[row * 264 + c4];
    }
#undef GEMM_PIPE
}

// ---------------------------------------------------------------------------
extern "C" void kernel_launch(void* const* d_in, const int* in_sizes, int n_in,
                              void* d_out, int out_size, void* d_ws, size_t ws_size,
                              hipStream_t stream) {
    const float* z      = (const float*)d_in[0];
    const float* ln1_g  = (const float*)d_in[1];
    const float* ln1_b  = (const float*)d_in[2];
    const float* proj_v = (const float*)d_in[3];
    const float* proj_g = (const float*)d_in[4];
    const float* proj_b = (const float*)d_in[5];
    const float* ff_v   = (const float*)d_in[6];
    const float* ff_g   = (const float*)d_in[7];
    const float* ff_b   = (const float*)d_in[8];
    const float* ln2_g  = (const float*)d_in[9];
    const float* ln2_b  = (const float*)d_in[10];
    const float* w1_v   = (const float*)d_in[11];
    const float* w1_g   = (const float*)d_in[12];
    const float* w1_b   = (const float*)d_in[13];
    const float* w2_v   = (const float*)d_in[14];
    const float* w2_g   = (const float*)d_in[15];
    const float* w2_b   = (const float*)d_in[16];
    float* out = (float*)d_out;

    char* p = (char*)d_ws;
    bf16_t* Wall = (bf16_t*)p; p += (size_t)1536 * 256 * 2;
    float* ctab  = (float*)p;  p += 8192 * 4;
    float* stab  = (float*)p;  p += 8192 * 4;
    // q/k: [bh][a][d]; vtb: [bh][d][a]; each 512*512*32 = TOK*256 elems
    bf16_t* qbf  = (bf16_t*)p; p += (size_t)TOK * 256 * 2;
    bf16_t* kbf  = (bf16_t*)p; p += (size_t)TOK * 256 * 2;
    bf16_t* vtb  = (bf16_t*)p; p += (size_t)TOK * 256 * 2;
    bf16_t* abuf = (bf16_t*)p; p += (size_t)TOK * 256 * 2;

    const bf16_t* Wqkv = Wall;
    const bf16_t* Wo   = Wall + (size_t)768 * 256;
    const bf16_t* W1   = Wall + (size_t)1024 * 256;
    const bf16_t* W2   = Wall + (size_t)1280 * 256;

    setup_kernel<<<1664, 64, 0, stream>>>(proj_v, proj_g, ff_v, ff_g,
                                          w1_v, w1_g, w2_v, w2_g,
                                          Wall, ctab, stab);
    qkv_kernel<<<TOK / 32, 256, 0, stream>>>(z, ln1_g, ln1_b, Wqkv, proj_b,
                                             ctab, stab, qbf, kbf, vtb);
    attn_kernel<<<64 * 8, 512, 0, stream>>>(qbf, kbf, vtb, abuf);
    tail_kernel<<<TOK / 32, 256, 0, stream>>>(abuf, Wo, ff_b, z, ln2_g, ln2_b,
                                              W1, w1_b, W2, w2_b, out);
}